// Round 1
// baseline (4137.949 us; speedup 1.0000x reference)
//
#include <hip/hip_runtime.h>

#define EPS 1e-5f

// ---------------- conv1: (64,3,142,142) -> (64,32,132,132), k=11, VALID ----------------
__global__ __launch_bounds__(256) void k_conv1(const float* __restrict__ x,
                                               const float* __restrict__ w,
                                               const float* __restrict__ bias,
                                               float* __restrict__ out)
{
    const int co = blockIdx.y, n = blockIdx.z;
    __shared__ float ws[363];
    for (int i = threadIdx.x; i < 363; i += 256) ws[i] = w[co * 363 + i];
    __syncthreads();
    const int g = blockIdx.x * 256 + threadIdx.x;
    if (g >= 132 * 33) return;          // 33 groups of 4 cover 132 exactly
    const int y = g / 33;
    const int x0 = (g - y * 33) * 4;
    float a0 = bias[co], a1 = a0, a2 = a0, a3 = a0;
    const float* xn = x + n * 3 * 142 * 142;
    for (int ci = 0; ci < 3; ++ci) {
        for (int ky = 0; ky < 11; ++ky) {
            const float* row = xn + (ci * 142 + y + ky) * 142 + x0;
            float r[14];
            #pragma unroll
            for (int i = 0; i < 14; ++i) r[i] = row[i];
            const float* wr = ws + (ci * 11 + ky) * 11;
            #pragma unroll
            for (int kx = 0; kx < 11; ++kx) {
                const float wv = wr[kx];
                a0 = fmaf(wv, r[kx],     a0);
                a1 = fmaf(wv, r[kx + 1], a1);
                a2 = fmaf(wv, r[kx + 2], a2);
                a3 = fmaf(wv, r[kx + 3], a3);
            }
        }
    }
    float* o = out + ((n * 32 + co) * 132 + y) * 132 + x0;
    o[0] = a0; o[1] = a1; o[2] = a2; o[3] = a3;
}

// ---------------- region layer: per-(8x8)-region BN+ReLU+3x3 same conv + residual ----
// Tiles: rows/cols split as 7 tiles of 18 plus remainder 6. Conv zero-pads at TILE edges.
__global__ __launch_bounds__(256) void k_region(const float* __restrict__ h1,
                                                const float* __restrict__ gg,
                                                const float* __restrict__ bb,
                                                const float* __restrict__ mm,
                                                const float* __restrict__ vv,
                                                const float* __restrict__ ww,
                                                const float* __restrict__ cb,
                                                float* __restrict__ out)
{
    __shared__ float t[32 * 20 * 20];   // padded tile, zero border, 51.2 KB
    const int reg = blockIdx.x;         // ri*8 + rj
    const int ri = reg >> 3, rj = reg & 7;
    const int n = blockIdx.y;
    const int Y0 = ri * 18, X0 = rj * 18;
    const int th = (ri < 7) ? 18 : 6, tw = (rj < 7) ? 18 : 6;

    for (int i = threadIdx.x; i < 32 * 20 * 20; i += 256) t[i] = 0.f;
    __syncthreads();

    const int npix = th * tw;
    for (int i = threadIdx.x; i < 32 * npix; i += 256) {
        const int ci = i / npix;
        const int p  = i - ci * npix;
        const int y  = p / tw;
        const int xx = p - y * tw;
        const float val = h1[((n * 32 + ci) * 132 + Y0 + y) * 132 + X0 + xx];
        const float sc  = gg[reg * 32 + ci] * rsqrtf(vv[reg * 32 + ci] + EPS);
        const float yv  = (val - mm[reg * 32 + ci]) * sc + bb[reg * 32 + ci];
        t[(ci * 20 + y + 1) * 20 + xx + 1] = fmaxf(yv, 0.f);
    }
    __syncthreads();

    const int nxp = tw >> 1;            // x-pairs per row (9 or 3)
    const int per_co = th * nxp;
    const int nunits = 32 * per_co;
    const float* wreg = ww + reg * (32 * 32 * 9);
    for (int u = threadIdx.x; u < nunits; u += 256) {
        const int co = u / per_co;
        const int p  = u - co * per_co;
        const int y  = p / nxp;
        const int xp = (p - y * nxp) * 2;
        float a0 = cb[reg * 32 + co], a1 = a0;
        const float* wc = wreg + co * (32 * 9);
        for (int ci = 0; ci < 32; ++ci) {
            const float* tp = t + (ci * 20 + y) * 20 + xp;  // padded coords: out(y,x) taps rows y..y+2
            const float* wp = wc + ci * 9;
            #pragma unroll
            for (int ky = 0; ky < 3; ++ky) {
                const float t0 = tp[ky * 20 + 0], t1 = tp[ky * 20 + 1];
                const float t2 = tp[ky * 20 + 2], t3 = tp[ky * 20 + 3];
                const float w0 = wp[ky * 3 + 0], w1 = wp[ky * 3 + 1], w2 = wp[ky * 3 + 2];
                a0 = fmaf(w0, t0, fmaf(w1, t1, fmaf(w2, t2, a0)));
                a1 = fmaf(w0, t1, fmaf(w1, t2, fmaf(w2, t3, a1)));
            }
        }
        const int Y = Y0 + y, X = X0 + xp;
        const int o = ((n * 32 + co) * 132 + Y) * 132 + X;
        out[o]     = a0 + h1[o];        // residual adds pre-BN input
        out[o + 1] = a1 + h1[o + 1];
    }
}

// ---------------- relu -> maxpool2x2 -> bn2 : (64,32,132,132) -> (64,32,66,66) --------
__global__ __launch_bounds__(256) void k_pool_bn(const float* __restrict__ in,
                                                 const float* __restrict__ g2,
                                                 const float* __restrict__ b2,
                                                 const float* __restrict__ m2,
                                                 const float* __restrict__ v2,
                                                 float* __restrict__ out)
{
    const int idx = blockIdx.x * 256 + threadIdx.x;
    if (idx >= 64 * 32 * 66 * 66) return;
    const int x = idx % 66;
    const int y = (idx / 66) % 66;
    const int c = (idx / (66 * 66)) % 32;
    const int n = idx / (66 * 66 * 32);
    const float* p = in + ((n * 32 + c) * 132 + 2 * y) * 132 + 2 * x;
    float mx = fmaxf(fmaxf(p[0], p[1]), fmaxf(p[132], p[133]));
    mx = fmaxf(mx, 0.f);                // relu commutes with max
    out[idx] = (mx - m2[c]) * (g2[c] * rsqrtf(v2[c] + EPS)) + b2[c];
}

// ---------------- generic direct conv (VALID) + relu, 16 out channels -----------------
template <int CIN, int KS, int STRIDE, int HIN, int HOUT>
__global__ __launch_bounds__(256) void k_conv(const float* __restrict__ in,
                                              const float* __restrict__ w,
                                              const float* __restrict__ bias,
                                              float* __restrict__ out)
{
    const int co = blockIdx.y, n = blockIdx.z;
    constexpr int GR  = (HOUT + 3) / 4;
    constexpr int WSZ = CIN * KS * KS;
    constexpr int LEN = KS + 3 * STRIDE;
    __shared__ float ws[WSZ];
    for (int i = threadIdx.x; i < WSZ; i += 256) ws[i] = w[co * WSZ + i];
    __syncthreads();
    const int g = blockIdx.x * 256 + threadIdx.x;
    if (g >= HOUT * GR) return;
    const int y = g / GR;
    int x0 = (g - y * GR) * 4;
    if (x0 > HOUT - 4) x0 = HOUT - 4;   // overlapping tail writes identical values
    float a0 = bias[co], a1 = a0, a2 = a0, a3 = a0;
    const float* base = in + n * CIN * HIN * HIN;
    for (int ci = 0; ci < CIN; ++ci) {
        for (int ky = 0; ky < KS; ++ky) {
            const float* row = base + (ci * HIN + y * STRIDE + ky) * HIN + x0 * STRIDE;
            float r[LEN];
            #pragma unroll
            for (int i = 0; i < LEN; ++i) r[i] = row[i];
            const float* wr = ws + (ci * KS + ky) * KS;
            #pragma unroll
            for (int kx = 0; kx < KS; ++kx) {
                const float wv = wr[kx];
                a0 = fmaf(wv, r[kx],              a0);
                a1 = fmaf(wv, r[kx + STRIDE],     a1);
                a2 = fmaf(wv, r[kx + 2 * STRIDE], a2);
                a3 = fmaf(wv, r[kx + 3 * STRIDE], a3);
            }
        }
    }
    float* o = out + ((n * 16 + co) * HOUT + y) * HOUT + x0;
    o[0] = fmaxf(a0, 0.f); o[1] = fmaxf(a1, 0.f);
    o[2] = fmaxf(a2, 0.f); o[3] = fmaxf(a3, 0.f);
}

// ---------------- fc GEMM: C[64][N] += A[64][K] * W[N][K]^T, split-K via atomics ------
__global__ __launch_bounds__(256) void k_fc(const float* __restrict__ A,
                                            const float* __restrict__ W,
                                            float* __restrict__ C,
                                            int N, int K, int kchunk)
{
    __shared__ float As[16][65];
    __shared__ float Bs[16][65];
    const int n0 = blockIdx.x * 64;
    const int kbeg = blockIdx.y * kchunk;
    const int tx = threadIdx.x & 15, ty = threadIdx.x >> 4;
    const int lk = threadIdx.x & 15;
    const int lm = threadIdx.x >> 4;
    float acc[4][4] = {};
    for (int k0 = kbeg; k0 < kbeg + kchunk; k0 += 16) {
        #pragma unroll
        for (int i = 0; i < 4; ++i) {
            const int m = lm + 16 * i;
            As[lk][m] = A[m * K + k0 + lk];
            const int nn = n0 + lm + 16 * i;
            Bs[lk][lm + 16 * i] = (nn < N) ? W[(long)nn * K + k0 + lk] : 0.f;
        }
        __syncthreads();
        #pragma unroll
        for (int kk = 0; kk < 16; ++kk) {
            float a[4], b[4];
            #pragma unroll
            for (int i = 0; i < 4; ++i) a[i] = As[kk][ty * 4 + i];
            #pragma unroll
            for (int j = 0; j < 4; ++j) b[j] = Bs[kk][tx * 4 + j];
            #pragma unroll
            for (int i = 0; i < 4; ++i)
                #pragma unroll
                for (int j = 0; j < 4; ++j)
                    acc[i][j] = fmaf(a[i], b[j], acc[i][j]);
        }
        __syncthreads();
    }
    #pragma unroll
    for (int i = 0; i < 4; ++i) {
        const int m = ty * 4 + i;
        #pragma unroll
        for (int j = 0; j < 4; ++j) {
            const int nn = n0 + tx * 4 + j;
            if (nn < N) atomicAdd(&C[m * N + nn], acc[i][j]);
        }
    }
}

__global__ __launch_bounds__(256) void k_bias_act(const float* __restrict__ C,
                                                  const float* __restrict__ bias,
                                                  float* __restrict__ out,
                                                  int N, int total, int relu)
{
    const int i = blockIdx.x * 256 + threadIdx.x;
    if (i >= total) return;
    float v = C[i] + bias[i % N];
    if (relu) v = fmaxf(v, 0.f);
    out[i] = v;
}

extern "C" void kernel_launch(void* const* d_in, const int* in_sizes, int n_in,
                              void* d_out, int out_size, void* d_ws, size_t ws_size,
                              hipStream_t stream)
{
    (void)in_sizes; (void)n_in; (void)out_size; (void)ws_size;
    const float* x       = (const float*)d_in[0];
    const float* conv1_w = (const float*)d_in[1];
    const float* conv1_b = (const float*)d_in[2];
    const float* rg_g    = (const float*)d_in[3];
    const float* rg_b    = (const float*)d_in[4];
    const float* rg_m    = (const float*)d_in[5];
    const float* rg_v    = (const float*)d_in[6];
    const float* rg_w    = (const float*)d_in[7];
    const float* rg_cb   = (const float*)d_in[8];
    const float* bn2_g   = (const float*)d_in[9];
    const float* bn2_b   = (const float*)d_in[10];
    const float* bn2_m   = (const float*)d_in[11];
    const float* bn2_v   = (const float*)d_in[12];
    const float* conv2_w = (const float*)d_in[13];
    const float* conv2_b = (const float*)d_in[14];
    const float* conv3_w = (const float*)d_in[15];
    const float* conv3_b = (const float*)d_in[16];
    const float* conv4_w = (const float*)d_in[17];
    const float* conv4_b = (const float*)d_in[18];
    const float* conv5_w = (const float*)d_in[19];
    const float* conv5_b = (const float*)d_in[20];
    const float* fc1_w   = (const float*)d_in[21];
    const float* fc1_b   = (const float*)d_in[22];
    const float* fc2_w   = (const float*)d_in[23];
    const float* fc2_b   = (const float*)d_in[24];
    const float* fc3_w   = (const float*)d_in[25];
    const float* fc3_b   = (const float*)d_in[26];

    float* ws = (float*)d_ws;
    // peak footprint: h1 + hr = 2 * 35,684,352 floats = 285.5 MB
    float* h1 = ws;                     // conv1 out (64,32,132,132)
    float* hr = ws + 35684352;          // region out, same shape
    float* hp = ws;                     // pooled (64,32,66,66): reuse h1 (dead after region)
    float* h3 = ws + 8921088;           // conv2 out (64,16,59,59)
    float* h4 = h3 + 3564544;           // conv3 out (64,16,52,52)
    float* h5 = h4 + 2768896;           // conv4 out (64,16,24,24)
    float* h6 = h5 + 589824;            // conv5 out (64,16,20,20) == fc1 input (64,6400)
    float* f1 = h6 + 409600;            // fc1 out (64,4096)
    float* f2 = f1 + 262144;            // fc2 out (64,2048)
    float* f3 = f2 + 131072;            // fc3 tmp (64,12)

    k_conv1<<<dim3(18, 32, 64), 256, 0, stream>>>(x, conv1_w, conv1_b, h1);
    k_region<<<dim3(64, 64), 256, 0, stream>>>(h1, rg_g, rg_b, rg_m, rg_v, rg_w, rg_cb, hr);
    k_pool_bn<<<dim3((64 * 32 * 66 * 66 + 255) / 256), 256, 0, stream>>>(hr, bn2_g, bn2_b, bn2_m, bn2_v, hp);
    k_conv<32, 8, 1, 66, 59><<<dim3(4, 16, 64), 256, 0, stream>>>(hp, conv2_w, conv2_b, h3);
    k_conv<16, 8, 1, 59, 52><<<dim3(3, 16, 64), 256, 0, stream>>>(h3, conv3_w, conv3_b, h4);
    k_conv<16, 6, 2, 52, 24><<<dim3(1, 16, 64), 256, 0, stream>>>(h4, conv4_w, conv4_b, h5);
    k_conv<16, 5, 1, 24, 20><<<dim3(1, 16, 64), 256, 0, stream>>>(h5, conv5_w, conv5_b, h6);

    hipMemsetAsync(f1, 0, 262144 * sizeof(float), stream);
    k_fc<<<dim3(64, 4), 256, 0, stream>>>(h6, fc1_w, f1, 4096, 6400, 1600);
    k_bias_act<<<dim3((262144 + 255) / 256), 256, 0, stream>>>(f1, fc1_b, f1, 4096, 262144, 1);

    hipMemsetAsync(f2, 0, 131072 * sizeof(float), stream);
    k_fc<<<dim3(32, 8), 256, 0, stream>>>(f1, fc2_w, f2, 2048, 4096, 512);
    k_bias_act<<<dim3((131072 + 255) / 256), 256, 0, stream>>>(f2, fc2_b, f2, 2048, 131072, 1);

    hipMemsetAsync(f3, 0, 768 * sizeof(float), stream);
    k_fc<<<dim3(1, 8), 256, 0, stream>>>(f2, fc3_w, f3, 12, 2048, 256);
    k_bias_act<<<dim3(3), 256, 0, stream>>>(f3, fc3_b, (float*)d_out, 12, 768, 0);
}

// Round 2
// 2013.407 us; speedup vs baseline: 2.0552x; 2.0552x over previous
//
#include <hip/hip_runtime.h>

#define EPS 1e-5f

// ---------------- 4x4-register-blocked direct conv (VALID, stride 1) ------------------
// Each thread computes a 4x4 output tile: rows of (KS+3) inputs are loaded once and
// feed up to 4 output rows (ky = jr - oy), giving ~10:1 FMA:load ratio.
template <int CIN, int KS, int HIN, int HOUT>
__global__ __launch_bounds__(256) void k_conv4x4(const float* __restrict__ in,
                                                 const float* __restrict__ w,
                                                 const float* __restrict__ bias,
                                                 float* __restrict__ out,
                                                 int cout, int relu)
{
    const int co = blockIdx.y, n = blockIdx.z;
    constexpr int GR   = (HOUT + 3) / 4;
    constexpr int WSZ  = CIN * KS * KS;
    constexpr int LEN  = KS + 3;
    constexpr int NROW = KS + 3;
    __shared__ float ws[WSZ];
    for (int i = threadIdx.x; i < WSZ; i += 256) ws[i] = w[co * WSZ + i];
    __syncthreads();
    const int g = blockIdx.x * 256 + threadIdx.x;
    if (g >= GR * GR) return;
    int y0 = (g / GR) * 4; if (y0 > HOUT - 4) y0 = HOUT - 4;   // clamped tiles recompute
    int x0 = (g % GR) * 4; if (x0 > HOUT - 4) x0 = HOUT - 4;   // identical values: benign
    const float bv = bias[co];
    float acc[4][4];
    #pragma unroll
    for (int i = 0; i < 4; ++i)
        #pragma unroll
        for (int j = 0; j < 4; ++j) acc[i][j] = bv;
    const float* base = in + (long)n * CIN * HIN * HIN;
    for (int ci = 0; ci < CIN; ++ci) {
        #pragma unroll
        for (int jr = 0; jr < NROW; ++jr) {
            const float* row = base + ((long)ci * HIN + y0 + jr) * HIN + x0;
            float r[LEN];
            #pragma unroll
            for (int i = 0; i < LEN; ++i) r[i] = row[i];
            #pragma unroll
            for (int oy = 0; oy < 4; ++oy) {
                const int ky = jr - oy;
                if (ky < 0 || ky >= KS) continue;
                const float* wr = ws + (ci * KS + ky) * KS;
                #pragma unroll
                for (int kx = 0; kx < KS; ++kx) {
                    const float wv = wr[kx];
                    acc[oy][0] = fmaf(wv, r[kx],     acc[oy][0]);
                    acc[oy][1] = fmaf(wv, r[kx + 1], acc[oy][1]);
                    acc[oy][2] = fmaf(wv, r[kx + 2], acc[oy][2]);
                    acc[oy][3] = fmaf(wv, r[kx + 3], acc[oy][3]);
                }
            }
        }
    }
    #pragma unroll
    for (int oy = 0; oy < 4; ++oy) {
        float* o = out + (((long)n * cout + co) * HOUT + y0 + oy) * HOUT + x0;
        #pragma unroll
        for (int j = 0; j < 4; ++j)
            o[j] = relu ? fmaxf(acc[oy][j], 0.f) : acc[oy][j];
    }
}

// ---------------- region layer: per-(8x8)-region BN+ReLU+3x3 same conv + residual ----
// Thread = (co, 3-row group); computes full tile width. Weights loaded once per 54
// outputs; LDS read as 16B-aligned windows shared across the 3 output rows.
template <int TH, int TW>
__device__ void region_body(const float* __restrict__ h1,
                            const float* __restrict__ gg, const float* __restrict__ bb,
                            const float* __restrict__ mm, const float* __restrict__ vv,
                            const float* __restrict__ ww, const float* __restrict__ cb,
                            float* __restrict__ out, float* t, int reg, int n, int Y0, int X0)
{
    for (int i = threadIdx.x; i < 32 * 20 * 20; i += 256) t[i] = 0.f;
    __syncthreads();
    constexpr int NPIX = TH * TW;
    for (int i = threadIdx.x; i < 32 * NPIX; i += 256) {
        const int ci = i / NPIX;
        const int p  = i - ci * NPIX;
        const int y  = p / TW;
        const int x  = p - y * TW;
        const float val = h1[((long)(n * 32 + ci) * 132 + Y0 + y) * 132 + X0 + x];
        const float sc  = gg[reg * 32 + ci] * rsqrtf(vv[reg * 32 + ci] + EPS);
        const float yv  = (val - mm[reg * 32 + ci]) * sc + bb[reg * 32 + ci];
        t[(ci * 20 + y + 1) * 20 + x + 1] = fmaxf(yv, 0.f);
    }
    __syncthreads();
    constexpr int NYG = TH / 3;
    const int u = threadIdx.x;
    if (u >= 32 * NYG) return;
    const int co = u / NYG;
    const int y0 = (u - co * NYG) * 3;
    const float bv = cb[reg * 32 + co];
    float acc[3][TW];
    #pragma unroll
    for (int oy = 0; oy < 3; ++oy)
        #pragma unroll
        for (int x = 0; x < TW; ++x) acc[oy][x] = bv;
    const float* wc = ww + ((long)reg * 32 + co) * (32 * 9);
    for (int ci = 0; ci < 32; ++ci) {
        float wv[9];
        #pragma unroll
        for (int k = 0; k < 9; ++k) wv[k] = wc[ci * 9 + k];
        const float* tb = t + (ci * 20 + y0) * 20;
        #pragma unroll
        for (int d = 0; d < 5; ++d) {             // padded rows y0+d feed oy = d-2..d
            float win[TW + 2];
            #pragma unroll
            for (int i = 0; i < TW + 2; ++i) win[i] = tb[d * 20 + i];
            #pragma unroll
            for (int oy = 0; oy < 3; ++oy) {
                const int ky = d - oy;
                if (ky < 0 || ky > 2) continue;
                const float w0 = wv[ky * 3], w1 = wv[ky * 3 + 1], w2 = wv[ky * 3 + 2];
                #pragma unroll
                for (int x = 0; x < TW; ++x)
                    acc[oy][x] = fmaf(w0, win[x], fmaf(w1, win[x + 1], fmaf(w2, win[x + 2], acc[oy][x])));
            }
        }
    }
    #pragma unroll
    for (int oy = 0; oy < 3; ++oy) {
        const long o = ((long)(n * 32 + co) * 132 + Y0 + y0 + oy) * 132 + X0;
        #pragma unroll
        for (int x = 0; x < TW; ++x) out[o + x] = acc[oy][x] + h1[o + x];  // residual = pre-BN input
    }
}

__global__ __launch_bounds__(256) void k_region(const float* __restrict__ h1,
                                                const float* __restrict__ gg,
                                                const float* __restrict__ bb,
                                                const float* __restrict__ mm,
                                                const float* __restrict__ vv,
                                                const float* __restrict__ ww,
                                                const float* __restrict__ cb,
                                                float* __restrict__ out)
{
    __shared__ __align__(16) float t[32 * 20 * 20];  // padded tile, zero border, 51.2 KB
    const int reg = blockIdx.x;
    const int ri = reg >> 3, rj = reg & 7;
    const int n = blockIdx.y;
    const int Y0 = ri * 18, X0 = rj * 18;
    if (ri < 7 && rj < 7)      region_body<18, 18>(h1, gg, bb, mm, vv, ww, cb, out, t, reg, n, Y0, X0);
    else if (ri < 7)           region_body<18, 6>(h1, gg, bb, mm, vv, ww, cb, out, t, reg, n, Y0, X0);
    else if (rj < 7)           region_body<6, 18>(h1, gg, bb, mm, vv, ww, cb, out, t, reg, n, Y0, X0);
    else                       region_body<6, 6>(h1, gg, bb, mm, vv, ww, cb, out, t, reg, n, Y0, X0);
}

// ---------------- relu -> maxpool2x2 -> bn2 : (64,32,132,132) -> (64,32,66,66) --------
__global__ __launch_bounds__(256) void k_pool_bn(const float* __restrict__ in,
                                                 const float* __restrict__ g2,
                                                 const float* __restrict__ b2,
                                                 const float* __restrict__ m2,
                                                 const float* __restrict__ v2,
                                                 float* __restrict__ out)
{
    const int idx = blockIdx.x * 256 + threadIdx.x;
    if (idx >= 64 * 32 * 66 * 66) return;
    const int x = idx % 66;
    const int y = (idx / 66) % 66;
    const int c = (idx / (66 * 66)) % 32;
    const int n = idx / (66 * 66 * 32);
    const float* p = in + ((n * 32 + c) * 132 + 2 * y) * 132 + 2 * x;
    float mx = fmaxf(fmaxf(p[0], p[1]), fmaxf(p[132], p[133]));
    mx = fmaxf(mx, 0.f);                // relu commutes with max
    out[idx] = (mx - m2[c]) * (g2[c] * rsqrtf(v2[c] + EPS)) + b2[c];
}

// ---------------- generic direct conv (VALID) + relu (used for strided conv4) --------
template <int CIN, int KS, int STRIDE, int HIN, int HOUT>
__global__ __launch_bounds__(256) void k_conv(const float* __restrict__ in,
                                              const float* __restrict__ w,
                                              const float* __restrict__ bias,
                                              float* __restrict__ out)
{
    const int co = blockIdx.y, n = blockIdx.z;
    constexpr int GR  = (HOUT + 3) / 4;
    constexpr int WSZ = CIN * KS * KS;
    constexpr int LEN = KS + 3 * STRIDE;
    __shared__ float ws[WSZ];
    for (int i = threadIdx.x; i < WSZ; i += 256) ws[i] = w[co * WSZ + i];
    __syncthreads();
    const int g = blockIdx.x * 256 + threadIdx.x;
    if (g >= HOUT * GR) return;
    const int y = g / GR;
    int x0 = (g - y * GR) * 4;
    if (x0 > HOUT - 4) x0 = HOUT - 4;
    float a0 = bias[co], a1 = a0, a2 = a0, a3 = a0;
    const float* base = in + (long)n * CIN * HIN * HIN;
    for (int ci = 0; ci < CIN; ++ci) {
        for (int ky = 0; ky < KS; ++ky) {
            const float* row = base + ((long)ci * HIN + y * STRIDE + ky) * HIN + x0 * STRIDE;
            float r[LEN];
            #pragma unroll
            for (int i = 0; i < LEN; ++i) r[i] = row[i];
            const float* wr = ws + (ci * KS + ky) * KS;
            #pragma unroll
            for (int kx = 0; kx < KS; ++kx) {
                const float wv = wr[kx];
                a0 = fmaf(wv, r[kx],              a0);
                a1 = fmaf(wv, r[kx + STRIDE],     a1);
                a2 = fmaf(wv, r[kx + 2 * STRIDE], a2);
                a3 = fmaf(wv, r[kx + 3 * STRIDE], a3);
            }
        }
    }
    float* o = out + (((long)n * 16 + co) * HOUT + y) * HOUT + x0;
    o[0] = fmaxf(a0, 0.f); o[1] = fmaxf(a1, 0.f);
    o[2] = fmaxf(a2, 0.f); o[3] = fmaxf(a3, 0.f);
}

// ---------------- fc GEMM: C[64][N] += A[64][K] * W[N][K]^T, split-K via atomics ------
__global__ __launch_bounds__(256) void k_fc(const float* __restrict__ A,
                                            const float* __restrict__ W,
                                            float* __restrict__ C,
                                            int N, int K, int kchunk)
{
    __shared__ float As[16][65];
    __shared__ float Bs[16][65];
    const int n0 = blockIdx.x * 64;
    const int kbeg = blockIdx.y * kchunk;
    const int tx = threadIdx.x & 15, ty = threadIdx.x >> 4;
    const int lk = threadIdx.x & 15;
    const int lm = threadIdx.x >> 4;
    float acc[4][4] = {};
    for (int k0 = kbeg; k0 < kbeg + kchunk; k0 += 16) {
        #pragma unroll
        for (int i = 0; i < 4; ++i) {
            const int m = lm + 16 * i;
            As[lk][m] = A[m * K + k0 + lk];
            const int nn = n0 + lm + 16 * i;
            Bs[lk][lm + 16 * i] = (nn < N) ? W[(long)nn * K + k0 + lk] : 0.f;
        }
        __syncthreads();
        #pragma unroll
        for (int kk = 0; kk < 16; ++kk) {
            float a[4], b[4];
            #pragma unroll
            for (int i = 0; i < 4; ++i) a[i] = As[kk][ty * 4 + i];
            #pragma unroll
            for (int j = 0; j < 4; ++j) b[j] = Bs[kk][tx * 4 + j];
            #pragma unroll
            for (int i = 0; i < 4; ++i)
                #pragma unroll
                for (int j = 0; j < 4; ++j)
                    acc[i][j] = fmaf(a[i], b[j], acc[i][j]);
        }
        __syncthreads();
    }
    #pragma unroll
    for (int i = 0; i < 4; ++i) {
        const int m = ty * 4 + i;
        #pragma unroll
        for (int j = 0; j < 4; ++j) {
            const int nn = n0 + tx * 4 + j;
            if (nn < N) atomicAdd(&C[m * N + nn], acc[i][j]);
        }
    }
}

__global__ __launch_bounds__(256) void k_bias_act(const float* __restrict__ C,
                                                  const float* __restrict__ bias,
                                                  float* __restrict__ out,
                                                  int N, int total, int relu)
{
    const int i = blockIdx.x * 256 + threadIdx.x;
    if (i >= total) return;
    float v = C[i] + bias[i % N];
    if (relu) v = fmaxf(v, 0.f);
    out[i] = v;
}

extern "C" void kernel_launch(void* const* d_in, const int* in_sizes, int n_in,
                              void* d_out, int out_size, void* d_ws, size_t ws_size,
                              hipStream_t stream)
{
    (void)in_sizes; (void)n_in; (void)out_size; (void)ws_size;
    const float* x       = (const float*)d_in[0];
    const float* conv1_w = (const float*)d_in[1];
    const float* conv1_b = (const float*)d_in[2];
    const float* rg_g    = (const float*)d_in[3];
    const float* rg_b    = (const float*)d_in[4];
    const float* rg_m    = (const float*)d_in[5];
    const float* rg_v    = (const float*)d_in[6];
    const float* rg_w    = (const float*)d_in[7];
    const float* rg_cb   = (const float*)d_in[8];
    const float* bn2_g   = (const float*)d_in[9];
    const float* bn2_b   = (const float*)d_in[10];
    const float* bn2_m   = (const float*)d_in[11];
    const float* bn2_v   = (const float*)d_in[12];
    const float* conv2_w = (const float*)d_in[13];
    const float* conv2_b = (const float*)d_in[14];
    const float* conv3_w = (const float*)d_in[15];
    const float* conv3_b = (const float*)d_in[16];
    const float* conv4_w = (const float*)d_in[17];
    const float* conv4_b = (const float*)d_in[18];
    const float* conv5_w = (const float*)d_in[19];
    const float* conv5_b = (const float*)d_in[20];
    const float* fc1_w   = (const float*)d_in[21];
    const float* fc1_b   = (const float*)d_in[22];
    const float* fc2_w   = (const float*)d_in[23];
    const float* fc2_b   = (const float*)d_in[24];
    const float* fc3_w   = (const float*)d_in[25];
    const float* fc3_b   = (const float*)d_in[26];

    float* ws = (float*)d_ws;
    float* h1 = ws;                     // conv1 out (64,32,132,132)
    float* hr = ws + 35684352;          // region out, same shape
    float* hp = ws;                     // pooled (64,32,66,66): reuse h1 (dead after region)
    float* h3 = ws + 8921088;           // conv2 out (64,16,59,59)
    float* h4 = h3 + 3564544;           // conv3 out (64,16,52,52)
    float* h5 = h4 + 2768896;           // conv4 out (64,16,24,24)
    float* h6 = h5 + 589824;            // conv5 out (64,16,20,20) == fc1 input (64,6400)
    float* f1 = h6 + 409600;            // fc1 out (64,4096)
    float* f2 = f1 + 262144;            // fc2 out (64,2048)
    float* f3 = f2 + 131072;            // fc3 tmp (64,12)

    k_conv4x4<3, 11, 142, 132><<<dim3(5, 32, 64), 256, 0, stream>>>(x, conv1_w, conv1_b, h1, 32, 0);
    k_region<<<dim3(64, 64), 256, 0, stream>>>(h1, rg_g, rg_b, rg_m, rg_v, rg_w, rg_cb, hr);
    k_pool_bn<<<dim3((64 * 32 * 66 * 66 + 255) / 256), 256, 0, stream>>>(hr, bn2_g, bn2_b, bn2_m, bn2_v, hp);
    k_conv4x4<32, 8, 66, 59><<<dim3(1, 16, 64), 256, 0, stream>>>(hp, conv2_w, conv2_b, h3, 16, 1);
    k_conv4x4<16, 8, 59, 52><<<dim3(1, 16, 64), 256, 0, stream>>>(h3, conv3_w, conv3_b, h4, 16, 1);
    k_conv<16, 6, 2, 52, 24><<<dim3(1, 16, 64), 256, 0, stream>>>(h4, conv4_w, conv4_b, h5);
    k_conv4x4<16, 5, 24, 20><<<dim3(1, 16, 64), 256, 0, stream>>>(h5, conv5_w, conv5_b, h6, 16, 1);

    hipMemsetAsync(f1, 0, 262144 * sizeof(float), stream);
    k_fc<<<dim3(64, 4), 256, 0, stream>>>(h6, fc1_w, f1, 4096, 6400, 1600);
    k_bias_act<<<dim3((262144 + 255) / 256), 256, 0, stream>>>(f1, fc1_b, f1, 4096, 262144, 1);

    hipMemsetAsync(f2, 0, 131072 * sizeof(float), stream);
    k_fc<<<dim3(32, 8), 256, 0, stream>>>(f1, fc2_w, f2, 2048, 4096, 512);
    k_bias_act<<<dim3((131072 + 255) / 256), 256, 0, stream>>>(f2, fc2_b, f2, 2048, 131072, 1);

    hipMemsetAsync(f3, 0, 768 * sizeof(float), stream);
    k_fc<<<dim3(1, 8), 256, 0, stream>>>(f2, fc3_w, f3, 12, 2048, 256);
    k_bias_act<<<dim3(3), 256, 0, stream>>>(f3, fc3_b, (float*)d_out, 12, 768, 0);
}

// Round 3
// 1718.263 us; speedup vs baseline: 2.4082x; 1.1718x over previous
//
#include <hip/hip_runtime.h>

#define EPS 1e-5f

// ---------------- weight transpose: w[co][ci][ky][kx] -> wt[ci][ky][kx][co] ----------
__global__ void k_wt(const float* __restrict__ w, float* __restrict__ wt,
                     int CIN, int COUT, int KS)
{
    const int total = COUT * CIN * KS * KS;
    const int i = blockIdx.x * 256 + threadIdx.x;
    if (i >= total) return;
    const int per = CIN * KS * KS;
    const int co = i / per, rem = i - co * per;
    wt[rem * COUT + co] = w[i];
}

// ---------------- conv1: (64,3,142,142) -> (64,32,132,132), k=11, VALID ---------------
// Block = 4 rows x 132 cols x all 32 co. Input tile in LDS; weights via wave-uniform
// s_loads (wt layout [ci][ky][kx][co]); per tap: 1 ds_read + 32 v_fmac.
__global__ __launch_bounds__(576) void k_conv1_lds(const float* __restrict__ x,
                                                   const float* __restrict__ wt,
                                                   const float* __restrict__ bias,
                                                   float* __restrict__ out)
{
    __shared__ float t[3 * 14 * 142];       // 23.9 KB
    const int n = blockIdx.y;
    const int y0 = blockIdx.x * 4;          // 33 * 4 = 132 exact
    const int tid = threadIdx.x;
    const float* xn = x + (long)n * 3 * 142 * 142;
    for (int i = tid; i < 3 * 14 * 142; i += 576) {
        const int ci = i / (14 * 142);
        const int rem = i - ci * (14 * 142);
        const int r = rem / 142, c = rem - r * 142;
        t[i] = xn[((long)ci * 142 + y0 + r) * 142 + c];
    }
    __syncthreads();
    if (tid >= 528) return;
    const int yl = tid / 132, xx = tid - yl * 132;
    float acc[32];
    #pragma unroll
    for (int co = 0; co < 32; ++co) acc[co] = bias[co];
    #pragma unroll 1
    for (int ci = 0; ci < 3; ++ci) {
        #pragma unroll 1
        for (int ky = 0; ky < 11; ++ky) {
            const float* trow = t + (ci * 14 + yl + ky) * 142 + xx;
            const float* wrow = wt + (ci * 11 + ky) * (11 * 32);
            #pragma unroll
            for (int kx = 0; kx < 11; ++kx) {
                const float v = trow[kx];
                #pragma unroll
                for (int co = 0; co < 32; ++co)
                    acc[co] = fmaf(wrow[kx * 32 + co], v, acc[co]);
            }
        }
    }
    #pragma unroll
    for (int co = 0; co < 32; ++co)
        out[(((long)n * 32 + co) * 132 + y0 + yl) * 132 + xx] = acc[co];
}

// ---------------- generic stride-1 conv + relu, LDS-staged per-ci, transposed w ------
template <int CIN, int COUT, int KS, int HIN, int HOUT, int R>
__global__ __launch_bounds__(256) void k_convS(const float* __restrict__ in,
                                               const float* __restrict__ wt,
                                               const float* __restrict__ bias,
                                               float* __restrict__ out)
{
    constexpr int NR = R + KS - 1;
    constexpr int NPX = R * HOUT;
    __shared__ float buf[2][NR * HIN];
    const int n = blockIdx.y;
    int y0 = blockIdx.x * R; if (y0 > HOUT - R) y0 = HOUT - R;  // clamped tiles recompute
    const int tid = threadIdx.x;
    const float* base = in + (long)n * CIN * HIN * HIN;
    for (int i = tid; i < NR * HIN; i += 256) {
        const int r = i / HIN, c = i - r * HIN;
        buf[0][i] = base[(long)(y0 + r) * HIN + c];
    }
    __syncthreads();
    const int yl = tid / HOUT, x = tid - yl * HOUT;
    float acc[COUT];
    #pragma unroll
    for (int co = 0; co < COUT; ++co) acc[co] = bias[co];
    #pragma unroll 1
    for (int ci = 0; ci < CIN; ++ci) {
        const float* cur = buf[ci & 1];
        if (ci + 1 < CIN) {
            const float* src = base + (long)(ci + 1) * HIN * HIN;
            float* nxt = buf[(ci + 1) & 1];
            for (int i = tid; i < NR * HIN; i += 256) {
                const int r = i / HIN, c = i - r * HIN;
                nxt[i] = src[(long)(y0 + r) * HIN + c];
            }
        }
        if (tid < NPX) {
            const float* wci = wt + ci * (KS * KS * COUT);
            #pragma unroll 1
            for (int ky = 0; ky < KS; ++ky) {
                const float* trow = cur + (yl + ky) * HIN + x;
                const float* wrow = wci + ky * (KS * COUT);
                #pragma unroll
                for (int kx = 0; kx < KS; ++kx) {
                    const float v = trow[kx];
                    #pragma unroll
                    for (int co = 0; co < COUT; ++co)
                        acc[co] = fmaf(wrow[kx * COUT + co], v, acc[co]);
                }
            }
        }
        __syncthreads();
    }
    if (tid < NPX) {
        #pragma unroll
        for (int co = 0; co < COUT; ++co)
            out[(((long)n * COUT + co) * HOUT + y0 + yl) * HOUT + x] = fmaxf(acc[co], 0.f);
    }
}

// ---------------- region layer (unchanged from round 2) ------------------------------
template <int TH, int TW>
__device__ void region_body(const float* __restrict__ h1,
                            const float* __restrict__ gg, const float* __restrict__ bb,
                            const float* __restrict__ mm, const float* __restrict__ vv,
                            const float* __restrict__ ww, const float* __restrict__ cb,
                            float* __restrict__ out, float* t, int reg, int n, int Y0, int X0)
{
    for (int i = threadIdx.x; i < 32 * 20 * 20; i += 256) t[i] = 0.f;
    __syncthreads();
    constexpr int NPIX = TH * TW;
    for (int i = threadIdx.x; i < 32 * NPIX; i += 256) {
        const int ci = i / NPIX;
        const int p  = i - ci * NPIX;
        const int y  = p / TW;
        const int x  = p - y * TW;
        const float val = h1[((long)(n * 32 + ci) * 132 + Y0 + y) * 132 + X0 + x];
        const float sc  = gg[reg * 32 + ci] * rsqrtf(vv[reg * 32 + ci] + EPS);
        const float yv  = (val - mm[reg * 32 + ci]) * sc + bb[reg * 32 + ci];
        t[(ci * 20 + y + 1) * 20 + x + 1] = fmaxf(yv, 0.f);
    }
    __syncthreads();
    constexpr int NYG = TH / 3;
    const int u = threadIdx.x;
    if (u >= 32 * NYG) return;
    const int co = u / NYG;
    const int y0 = (u - co * NYG) * 3;
    const float bv = cb[reg * 32 + co];
    float acc[3][TW];
    #pragma unroll
    for (int oy = 0; oy < 3; ++oy)
        #pragma unroll
        for (int x = 0; x < TW; ++x) acc[oy][x] = bv;
    const float* wc = ww + ((long)reg * 32 + co) * (32 * 9);
    for (int ci = 0; ci < 32; ++ci) {
        float wv[9];
        #pragma unroll
        for (int k = 0; k < 9; ++k) wv[k] = wc[ci * 9 + k];
        const float* tb = t + (ci * 20 + y0) * 20;
        #pragma unroll
        for (int d = 0; d < 5; ++d) {
            float win[TW + 2];
            #pragma unroll
            for (int i = 0; i < TW + 2; ++i) win[i] = tb[d * 20 + i];
            #pragma unroll
            for (int oy = 0; oy < 3; ++oy) {
                const int ky = d - oy;
                if (ky < 0 || ky > 2) continue;
                const float w0 = wv[ky * 3], w1 = wv[ky * 3 + 1], w2 = wv[ky * 3 + 2];
                #pragma unroll
                for (int x = 0; x < TW; ++x)
                    acc[oy][x] = fmaf(w0, win[x], fmaf(w1, win[x + 1], fmaf(w2, win[x + 2], acc[oy][x])));
            }
        }
    }
    #pragma unroll
    for (int oy = 0; oy < 3; ++oy) {
        const long o = ((long)(n * 32 + co) * 132 + Y0 + y0 + oy) * 132 + X0;
        #pragma unroll
        for (int x = 0; x < TW; ++x) out[o + x] = acc[oy][x] + h1[o + x];
    }
}

__global__ __launch_bounds__(256) void k_region(const float* __restrict__ h1,
                                                const float* __restrict__ gg,
                                                const float* __restrict__ bb,
                                                const float* __restrict__ mm,
                                                const float* __restrict__ vv,
                                                const float* __restrict__ ww,
                                                const float* __restrict__ cb,
                                                float* __restrict__ out)
{
    __shared__ __align__(16) float t[32 * 20 * 20];
    const int reg = blockIdx.x;
    const int ri = reg >> 3, rj = reg & 7;
    const int n = blockIdx.y;
    const int Y0 = ri * 18, X0 = rj * 18;
    if (ri < 7 && rj < 7)      region_body<18, 18>(h1, gg, bb, mm, vv, ww, cb, out, t, reg, n, Y0, X0);
    else if (ri < 7)           region_body<18, 6>(h1, gg, bb, mm, vv, ww, cb, out, t, reg, n, Y0, X0);
    else if (rj < 7)           region_body<6, 18>(h1, gg, bb, mm, vv, ww, cb, out, t, reg, n, Y0, X0);
    else                       region_body<6, 6>(h1, gg, bb, mm, vv, ww, cb, out, t, reg, n, Y0, X0);
}

// ---------------- relu -> maxpool2x2 -> bn2 ------------------------------------------
__global__ __launch_bounds__(256) void k_pool_bn(const float* __restrict__ in,
                                                 const float* __restrict__ g2,
                                                 const float* __restrict__ b2,
                                                 const float* __restrict__ m2,
                                                 const float* __restrict__ v2,
                                                 float* __restrict__ out)
{
    const int idx = blockIdx.x * 256 + threadIdx.x;
    if (idx >= 64 * 32 * 66 * 66) return;
    const int x = idx % 66;
    const int y = (idx / 66) % 66;
    const int c = (idx / (66 * 66)) % 32;
    const int n = idx / (66 * 66 * 32);
    const float2* r0 = (const float2*)(in + (((long)n * 32 + c) * 132 + 2 * y) * 132);
    const float2* r1 = r0 + 66;
    const float2 a = r0[x], b = r1[x];
    float mx = fmaxf(fmaxf(a.x, a.y), fmaxf(b.x, b.y));
    mx = fmaxf(mx, 0.f);
    out[idx] = (mx - m2[c]) * (g2[c] * rsqrtf(v2[c] + EPS)) + b2[c];
}

// ---------------- strided conv (conv4 only) ------------------------------------------
template <int CIN, int KS, int STRIDE, int HIN, int HOUT>
__global__ __launch_bounds__(256) void k_conv(const float* __restrict__ in,
                                              const float* __restrict__ w,
                                              const float* __restrict__ bias,
                                              float* __restrict__ out)
{
    const int co = blockIdx.y, n = blockIdx.z;
    constexpr int GR  = (HOUT + 3) / 4;
    constexpr int WSZ = CIN * KS * KS;
    constexpr int LEN = KS + 3 * STRIDE;
    __shared__ float ws[WSZ];
    for (int i = threadIdx.x; i < WSZ; i += 256) ws[i] = w[co * WSZ + i];
    __syncthreads();
    const int g = blockIdx.x * 256 + threadIdx.x;
    if (g >= HOUT * GR) return;
    const int y = g / GR;
    int x0 = (g - y * GR) * 4;
    if (x0 > HOUT - 4) x0 = HOUT - 4;
    float a0 = bias[co], a1 = a0, a2 = a0, a3 = a0;
    const float* base = in + (long)n * CIN * HIN * HIN;
    for (int ci = 0; ci < CIN; ++ci) {
        for (int ky = 0; ky < KS; ++ky) {
            const float* row = base + ((long)ci * HIN + y * STRIDE + ky) * HIN + x0 * STRIDE;
            float r[LEN];
            #pragma unroll
            for (int i = 0; i < LEN; ++i) r[i] = row[i];
            const float* wr = ws + (ci * KS + ky) * KS;
            #pragma unroll
            for (int kx = 0; kx < KS; ++kx) {
                const float wv = wr[kx];
                a0 = fmaf(wv, r[kx],              a0);
                a1 = fmaf(wv, r[kx + STRIDE],     a1);
                a2 = fmaf(wv, r[kx + 2 * STRIDE], a2);
                a3 = fmaf(wv, r[kx + 3 * STRIDE], a3);
            }
        }
    }
    float* o = out + (((long)n * 16 + co) * HOUT + y) * HOUT + x0;
    o[0] = fmaxf(a0, 0.f); o[1] = fmaxf(a1, 0.f);
    o[2] = fmaxf(a2, 0.f); o[3] = fmaxf(a3, 0.f);
}

// ---------------- fc GEMM: C[64][N] += A[64][K] * W[N][K]^T, LDS-tiled, split-K ------
__global__ __launch_bounds__(256) void k_fc2(const float* __restrict__ A,
                                             const float* __restrict__ W,
                                             float* __restrict__ C,
                                             int N, int K, int kchunk)
{
    __shared__ float As[64][68];
    __shared__ float Bs[64][132];
    const int n0 = blockIdx.x * 128;
    const int kbeg = blockIdx.y * kchunk;
    const int tid = threadIdx.x;
    const int tm = tid >> 4, tn = tid & 15;
    const int am = tid >> 2, ac = tid & 3;
    const int bn = tid >> 1, bh = tid & 1;
    float acc[4][8] = {};
    for (int k0 = kbeg; k0 < kbeg + kchunk; k0 += 64) {
        #pragma unroll
        for (int q = 0; q < 4; ++q) {
            const int kk = ac * 16 + q * 4;
            const float4 v = *(const float4*)&A[(long)am * K + k0 + kk];
            As[kk + 0][am] = v.x; As[kk + 1][am] = v.y;
            As[kk + 2][am] = v.z; As[kk + 3][am] = v.w;
        }
        const int nn = n0 + bn;
        if (nn < N) {
            #pragma unroll
            for (int q = 0; q < 8; ++q) {
                const int kk = bh * 32 + q * 4;
                const float4 v = *(const float4*)&W[(long)nn * K + k0 + kk];
                Bs[kk + 0][bn] = v.x; Bs[kk + 1][bn] = v.y;
                Bs[kk + 2][bn] = v.z; Bs[kk + 3][bn] = v.w;
            }
        }
        __syncthreads();
        #pragma unroll 4
        for (int kk = 0; kk < 64; ++kk) {
            float a[4], b[8];
            #pragma unroll
            for (int i = 0; i < 4; ++i) a[i] = As[kk][tm * 4 + i];
            #pragma unroll
            for (int j = 0; j < 8; ++j) b[j] = Bs[kk][tn * 8 + j];
            #pragma unroll
            for (int i = 0; i < 4; ++i)
                #pragma unroll
                for (int j = 0; j < 8; ++j)
                    acc[i][j] = fmaf(a[i], b[j], acc[i][j]);
        }
        __syncthreads();
    }
    #pragma unroll
    for (int i = 0; i < 4; ++i) {
        const int m = tm * 4 + i;
        #pragma unroll
        for (int j = 0; j < 8; ++j) {
            const int nn = n0 + tn * 8 + j;
            if (nn < N) atomicAdd(&C[(long)m * N + nn], acc[i][j]);
        }
    }
}

__global__ __launch_bounds__(256) void k_bias_act(const float* __restrict__ C,
                                                  const float* __restrict__ bias,
                                                  float* __restrict__ out,
                                                  int N, int total, int relu)
{
    const int i = blockIdx.x * 256 + threadIdx.x;
    if (i >= total) return;
    float v = C[i] + bias[i % N];
    if (relu) v = fmaxf(v, 0.f);
    out[i] = v;
}

extern "C" void kernel_launch(void* const* d_in, const int* in_sizes, int n_in,
                              void* d_out, int out_size, void* d_ws, size_t ws_size,
                              hipStream_t stream)
{
    (void)in_sizes; (void)n_in; (void)out_size; (void)ws_size;
    const float* x       = (const float*)d_in[0];
    const float* conv1_w = (const float*)d_in[1];
    const float* conv1_b = (const float*)d_in[2];
    const float* rg_g    = (const float*)d_in[3];
    const float* rg_b    = (const float*)d_in[4];
    const float* rg_m    = (const float*)d_in[5];
    const float* rg_v    = (const float*)d_in[6];
    const float* rg_w    = (const float*)d_in[7];
    const float* rg_cb   = (const float*)d_in[8];
    const float* bn2_g   = (const float*)d_in[9];
    const float* bn2_b   = (const float*)d_in[10];
    const float* bn2_m   = (const float*)d_in[11];
    const float* bn2_v   = (const float*)d_in[12];
    const float* conv2_w = (const float*)d_in[13];
    const float* conv2_b = (const float*)d_in[14];
    const float* conv3_w = (const float*)d_in[15];
    const float* conv3_b = (const float*)d_in[16];
    const float* conv4_w = (const float*)d_in[17];
    const float* conv4_b = (const float*)d_in[18];
    const float* conv5_w = (const float*)d_in[19];
    const float* conv5_b = (const float*)d_in[20];
    const float* fc1_w   = (const float*)d_in[21];
    const float* fc1_b   = (const float*)d_in[22];
    const float* fc2_w   = (const float*)d_in[23];
    const float* fc2_b   = (const float*)d_in[24];
    const float* fc3_w   = (const float*)d_in[25];
    const float* fc3_b   = (const float*)d_in[26];

    float* ws = (float*)d_ws;
    float* h1 = ws;                     // conv1 out (64,32,132,132)
    float* hr = ws + 35684352;          // region out, same shape
    float* hp = ws;                     // pooled (64,32,66,66): reuse h1
    float* h3 = ws + 8921088;           // conv2 out
    float* h4 = h3 + 3564544;           // conv3 out
    float* h5 = h4 + 2768896;           // conv4 out
    float* h6 = h5 + 589824;            // conv5 out == fc1 input (64,6400)
    float* f1 = h6 + 409600;            // fc1 out (64,4096)
    float* f2 = f1 + 262144;            // fc2 out (64,2048)
    float* f3 = f2 + 131072;            // fc3 tmp (64,12)
    // transposed weights live inside the hr region during the phases where hr is dead
    float* wt1 = hr;                    // 11616 (used by conv1, before region writes hr)
    float* wt2 = hr + 16384;            // 32768 (written after pool_bn, hr dead)
    float* wt3 = hr + 49152;            // 16384
    float* wt5 = hr + 65536;            // 6400

    k_wt<<<dim3(46), 256, 0, stream>>>(conv1_w, wt1, 3, 32, 11);
    k_conv1_lds<<<dim3(33, 64), 576, 0, stream>>>(x, wt1, conv1_b, h1);
    k_region<<<dim3(64, 64), 256, 0, stream>>>(h1, rg_g, rg_b, rg_m, rg_v, rg_w, rg_cb, hr);
    k_pool_bn<<<dim3((64 * 32 * 66 * 66 + 255) / 256), 256, 0, stream>>>(hr, bn2_g, bn2_b, bn2_m, bn2_v, hp);

    k_wt<<<dim3(128), 256, 0, stream>>>(conv2_w, wt2, 32, 16, 8);
    k_wt<<<dim3(64), 256, 0, stream>>>(conv3_w, wt3, 16, 16, 8);
    k_wt<<<dim3(25), 256, 0, stream>>>(conv5_w, wt5, 16, 16, 5);

    k_convS<32, 16, 8, 66, 59, 4><<<dim3(15, 64), 256, 0, stream>>>(hp, wt2, conv2_b, h3);
    k_convS<16, 16, 8, 59, 52, 4><<<dim3(13, 64), 256, 0, stream>>>(h3, wt3, conv3_b, h4);
    k_conv<16, 6, 2, 52, 24><<<dim3(1, 16, 64), 256, 0, stream>>>(h4, conv4_w, conv4_b, h5);
    k_convS<16, 16, 5, 24, 20, 10><<<dim3(2, 64), 256, 0, stream>>>(h5, wt5, conv5_b, h6);

    hipMemsetAsync(f1, 0, 262144 * sizeof(float), stream);
    k_fc2<<<dim3(32, 10), 256, 0, stream>>>(h6, fc1_w, f1, 4096, 6400, 640);
    k_bias_act<<<dim3((262144 + 255) / 256), 256, 0, stream>>>(f1, fc1_b, f1, 4096, 262144, 1);

    hipMemsetAsync(f2, 0, 131072 * sizeof(float), stream);
    k_fc2<<<dim3(16, 16), 256, 0, stream>>>(f1, fc2_w, f2, 2048, 4096, 256);
    k_bias_act<<<dim3((131072 + 255) / 256), 256, 0, stream>>>(f2, fc2_b, f2, 2048, 131072, 1);

    hipMemsetAsync(f3, 0, 768 * sizeof(float), stream);
    k_fc2<<<dim3(1, 16), 256, 0, stream>>>(f2, fc3_w, f3, 12, 2048, 128);
    k_bias_act<<<dim3(3), 256, 0, stream>>>(f3, fc3_b, (float*)d_out, 12, 768, 0);
}

// Round 4
// 1463.449 us; speedup vs baseline: 2.8275x; 1.1741x over previous
//
#include <hip/hip_runtime.h>

#define EPS 1e-5f

typedef __attribute__((ext_vector_type(8)))  __bf16 bf16x8;
typedef __attribute__((ext_vector_type(16))) float  f32x16;

// ---------------- weight transpose: w[co][ci][ky][kx] -> wt[ci][ky][kx][co] ----------
__global__ void k_wt(const float* __restrict__ w, float* __restrict__ wt,
                     int CIN, int COUT, int KS)
{
    const int total = COUT * CIN * KS * KS;
    const int i = blockIdx.x * 256 + threadIdx.x;
    if (i >= total) return;
    const int per = CIN * KS * KS;
    const int co = i / per, rem = i - co * per;
    wt[rem * COUT + co] = w[i];
}

// ---------------- conv1: (64,3,142,142) -> (64,32,132,132), k=11, VALID ---------------
__global__ __launch_bounds__(576) void k_conv1_lds(const float* __restrict__ x,
                                                   const float* __restrict__ wt,
                                                   const float* __restrict__ bias,
                                                   float* __restrict__ out)
{
    __shared__ float t[3 * 14 * 142];
    const int n = blockIdx.y;
    const int y0 = blockIdx.x * 4;
    const int tid = threadIdx.x;
    const float* xn = x + (long)n * 3 * 142 * 142;
    for (int i = tid; i < 3 * 14 * 142; i += 576) {
        const int ci = i / (14 * 142);
        const int rem = i - ci * (14 * 142);
        const int r = rem / 142, c = rem - r * 142;
        t[i] = xn[((long)ci * 142 + y0 + r) * 142 + c];
    }
    __syncthreads();
    if (tid >= 528) return;
    const int yl = tid / 132, xx = tid - yl * 132;
    float acc[32];
    #pragma unroll
    for (int co = 0; co < 32; ++co) acc[co] = bias[co];
    #pragma unroll 1
    for (int ci = 0; ci < 3; ++ci) {
        #pragma unroll 1
        for (int ky = 0; ky < 11; ++ky) {
            const float* trow = t + (ci * 14 + yl + ky) * 142 + xx;
            const float* wrow = wt + (ci * 11 + ky) * (11 * 32);
            #pragma unroll
            for (int kx = 0; kx < 11; ++kx) {
                const float v = trow[kx];
                #pragma unroll
                for (int co = 0; co < 32; ++co)
                    acc[co] = fmaf(wrow[kx * 32 + co], v, acc[co]);
            }
        }
    }
    #pragma unroll
    for (int co = 0; co < 32; ++co)
        out[(((long)n * 32 + co) * 132 + y0 + yl) * 132 + xx] = acc[co];
}

// ---------------- generic stride-1 conv + relu, LDS-staged per-ci, transposed w ------
template <int CIN, int COUT, int KS, int HIN, int HOUT, int R>
__global__ __launch_bounds__(256) void k_convS(const float* __restrict__ in,
                                               const float* __restrict__ wt,
                                               const float* __restrict__ bias,
                                               float* __restrict__ out)
{
    constexpr int NR = R + KS - 1;
    constexpr int NPX = R * HOUT;
    __shared__ float buf[2][NR * HIN];
    const int n = blockIdx.y;
    int y0 = blockIdx.x * R; if (y0 > HOUT - R) y0 = HOUT - R;
    const int tid = threadIdx.x;
    const float* base = in + (long)n * CIN * HIN * HIN;
    for (int i = tid; i < NR * HIN; i += 256) {
        const int r = i / HIN, c = i - r * HIN;
        buf[0][i] = base[(long)(y0 + r) * HIN + c];
    }
    __syncthreads();
    const int yl = tid / HOUT, x = tid - yl * HOUT;
    float acc[COUT];
    #pragma unroll
    for (int co = 0; co < COUT; ++co) acc[co] = bias[co];
    #pragma unroll 1
    for (int ci = 0; ci < CIN; ++ci) {
        const float* cur = buf[ci & 1];
        if (ci + 1 < CIN) {
            const float* src = base + (long)(ci + 1) * HIN * HIN;
            float* nxt = buf[(ci + 1) & 1];
            for (int i = tid; i < NR * HIN; i += 256) {
                const int r = i / HIN, c = i - r * HIN;
                nxt[i] = src[(long)(y0 + r) * HIN + c];
            }
        }
        if (tid < NPX) {
            const float* wci = wt + ci * (KS * KS * COUT);
            #pragma unroll 1
            for (int ky = 0; ky < KS; ++ky) {
                const float* trow = cur + (yl + ky) * HIN + x;
                const float* wrow = wci + ky * (KS * COUT);
                #pragma unroll
                for (int kx = 0; kx < KS; ++kx) {
                    const float v = trow[kx];
                    #pragma unroll
                    for (int co = 0; co < COUT; ++co)
                        acc[co] = fmaf(wrow[kx * COUT + co], v, acc[co]);
                }
            }
        }
        __syncthreads();
    }
    if (tid < NPX) {
        #pragma unroll
        for (int co = 0; co < COUT; ++co)
            out[(((long)n * COUT + co) * HOUT + y0 + yl) * HOUT + x] = fmaxf(acc[co], 0.f);
    }
}

// ---------------- region layer via MFMA: per-region bf16 implicit GEMM ---------------
// out[co][pix] = sum_{k=tap*32+ci} W[co][k] * act[k][pix];  M=32 co, K=288, N=pixels.
// A (weights) preloaded to 72 VGPRs; K-loop = 1 ds_read_b128 + 1 mfma_32x32x16_bf16.
template <int TH, int TW, int NIMG>
__device__ void region_mfma_body(const float* __restrict__ h1,
                                 const float* __restrict__ gg, const float* __restrict__ bb,
                                 const float* __restrict__ mm, const float* __restrict__ vv,
                                 const float* __restrict__ ww, const float* __restrict__ cb,
                                 float* __restrict__ out,
                                 __bf16* act, __bf16* wlds,
                                 float* sc_s, float* sh_s, float* cb_s,
                                 int reg, int n0, int Y0, int X0)
{
    constexpr int PW   = TW + 2;
    constexpr int ROWS = TH + 2;
    constexpr int NP   = TH * TW;
    constexpr int NPT  = (NP + 31) / 32;
    const int tid  = threadIdx.x;
    const int lane = tid & 63;
    const int wv   = tid >> 6;
    const int half = lane >> 5;
    const int l31  = lane & 31;

    if (tid < 32) {
        const float sc = gg[reg * 32 + tid] * rsqrtf(vv[reg * 32 + tid] + EPS);
        sc_s[tid] = sc;
        sh_s[tid] = bb[reg * 32 + tid] - mm[reg * 32 + tid] * sc;
        cb_s[tid] = cb[reg * 32 + tid];
    }
    // weights -> LDS bf16, layout [co][tap][ci]
    for (int i = tid; i < 9216; i += 256) {
        const int co = i / 288, r = i - co * 288;
        const int ci = r / 9, tap = r - ci * 9;
        wlds[(co * 9 + tap) * 32 + ci] = (__bf16)ww[(long)reg * 9216 + i];
    }
    // zero act (borders stay zero across images; interior rewritten per image)
    for (int i = tid; i < ROWS * PW * 40; i += 256) act[i] = (__bf16)0.f;
    __syncthreads();

    // preload A fragments: A[m=co][k], k = c*16 + half*8 + j -> ci = (c&1)*16+half*8+j
    bf16x8 afrag[18];
    #pragma unroll
    for (int c = 0; c < 18; ++c) {
        const int tap = c >> 1;
        const int cib = (c & 1) * 16 + half * 8;
        afrag[c] = *(const bf16x8*)&wlds[(l31 * 9 + tap) * 32 + cib];
    }

    for (int img = 0; img < NIMG; ++img) {
        const int n = n0 + img;
        // stage BN+ReLU tile into padded LDS, bf16, layout [row][col][40]
        for (int i = tid; i < 32 * NP; i += 256) {
            const int ci = i / NP, p = i - ci * NP;
            const int y = p / TW, x = p - y * TW;
            const float val = h1[(((long)n * 32 + ci) * 132 + Y0 + y) * 132 + X0 + x];
            const float af = fmaxf(val * sc_s[ci] + sh_s[ci], 0.f);
            act[((y + 1) * PW + (x + 1)) * 40 + ci] = (__bf16)af;
        }
        __syncthreads();
        for (int pt = wv; pt < NPT; pt += 4) {
            const int p = pt * 32 + l31;
            const bool valid = p < NP;
            const int pc = valid ? p : 0;
            const int y = pc / TW, x = pc - y * TW;
            f32x16 acc = {};
            #pragma unroll
            for (int c = 0; c < 18; ++c) {
                const int tap = c >> 1;
                const int ky = tap / 3, kx = tap - ky * 3;
                const bf16x8 bfr = *(const bf16x8*)
                    &act[((y + ky) * PW + (x + kx)) * 40 + (c & 1) * 16 + half * 8];
                acc = __builtin_amdgcn_mfma_f32_32x32x16_bf16(afrag[c], bfr, acc, 0, 0, 0);
            }
            if (valid) {
                #pragma unroll
                for (int r = 0; r < 16; ++r) {
                    const int co = (r & 3) + 8 * (r >> 2) + 4 * half;
                    const long o = (((long)n * 32 + co) * 132 + Y0 + y) * 132 + X0 + x;
                    out[o] = acc[r] + cb_s[co] + h1[o];   // conv + bias + residual(pre-BN)
                }
            }
        }
        __syncthreads();
    }
}

__global__ __launch_bounds__(256) void k_region_mfma(const float* __restrict__ h1,
                                                     const float* __restrict__ gg,
                                                     const float* __restrict__ bb,
                                                     const float* __restrict__ mm,
                                                     const float* __restrict__ vv,
                                                     const float* __restrict__ ww,
                                                     const float* __restrict__ cb,
                                                     float* __restrict__ out)
{
    __shared__ __align__(16) __bf16 act[20 * 20 * 40];   // 32.0 KB
    __shared__ __align__(16) __bf16 wlds[9216];          // 18.4 KB
    __shared__ float sc_s[32], sh_s[32], cb_s[32];
    const int reg = blockIdx.x;
    const int ri = reg >> 3, rj = reg & 7;
    const int n0 = blockIdx.y * 8;
    const int Y0 = ri * 18, X0 = rj * 18;
    if (ri < 7 && rj < 7)
        region_mfma_body<18, 18, 8>(h1, gg, bb, mm, vv, ww, cb, out, act, wlds, sc_s, sh_s, cb_s, reg, n0, Y0, X0);
    else if (ri < 7)
        region_mfma_body<18, 6, 8>(h1, gg, bb, mm, vv, ww, cb, out, act, wlds, sc_s, sh_s, cb_s, reg, n0, Y0, X0);
    else if (rj < 7)
        region_mfma_body<6, 18, 8>(h1, gg, bb, mm, vv, ww, cb, out, act, wlds, sc_s, sh_s, cb_s, reg, n0, Y0, X0);
    else
        region_mfma_body<6, 6, 8>(h1, gg, bb, mm, vv, ww, cb, out, act, wlds, sc_s, sh_s, cb_s, reg, n0, Y0, X0);
}

// ---------------- relu -> maxpool2x2 -> bn2 ------------------------------------------
__global__ __launch_bounds__(256) void k_pool_bn(const float* __restrict__ in,
                                                 const float* __restrict__ g2,
                                                 const float* __restrict__ b2,
                                                 const float* __restrict__ m2,
                                                 const float* __restrict__ v2,
                                                 float* __restrict__ out)
{
    const int idx = blockIdx.x * 256 + threadIdx.x;
    if (idx >= 64 * 32 * 66 * 66) return;
    const int x = idx % 66;
    const int y = (idx / 66) % 66;
    const int c = (idx / (66 * 66)) % 32;
    const int n = idx / (66 * 66 * 32);
    const float2* r0 = (const float2*)(in + (((long)n * 32 + c) * 132 + 2 * y) * 132);
    const float2* r1 = r0 + 66;
    const float2 a = r0[x], b = r1[x];
    float mx = fmaxf(fmaxf(a.x, a.y), fmaxf(b.x, b.y));
    mx = fmaxf(mx, 0.f);
    out[idx] = (mx - m2[c]) * (g2[c] * rsqrtf(v2[c] + EPS)) + b2[c];
}

// ---------------- strided conv (conv4 only) ------------------------------------------
template <int CIN, int KS, int STRIDE, int HIN, int HOUT>
__global__ __launch_bounds__(256) void k_conv(const float* __restrict__ in,
                                              const float* __restrict__ w,
                                              const float* __restrict__ bias,
                                              float* __restrict__ out)
{
    const int co = blockIdx.y, n = blockIdx.z;
    constexpr int GR  = (HOUT + 3) / 4;
    constexpr int WSZ = CIN * KS * KS;
    constexpr int LEN = KS + 3 * STRIDE;
    __shared__ float ws[WSZ];
    for (int i = threadIdx.x; i < WSZ; i += 256) ws[i] = w[co * WSZ + i];
    __syncthreads();
    const int g = blockIdx.x * 256 + threadIdx.x;
    if (g >= HOUT * GR) return;
    const int y = g / GR;
    int x0 = (g - y * GR) * 4;
    if (x0 > HOUT - 4) x0 = HOUT - 4;
    float a0 = bias[co], a1 = a0, a2 = a0, a3 = a0;
    const float* base = in + (long)n * CIN * HIN * HIN;
    for (int ci = 0; ci < CIN; ++ci) {
        for (int ky = 0; ky < KS; ++ky) {
            const float* row = base + ((long)ci * HIN + y * STRIDE + ky) * HIN + x0 * STRIDE;
            float r[LEN];
            #pragma unroll
            for (int i = 0; i < LEN; ++i) r[i] = row[i];
            const float* wr = ws + (ci * KS + ky) * KS;
            #pragma unroll
            for (int kx = 0; kx < KS; ++kx) {
                const float wv = wr[kx];
                a0 = fmaf(wv, r[kx],              a0);
                a1 = fmaf(wv, r[kx + STRIDE],     a1);
                a2 = fmaf(wv, r[kx + 2 * STRIDE], a2);
                a3 = fmaf(wv, r[kx + 3 * STRIDE], a3);
            }
        }
    }
    float* o = out + (((long)n * 16 + co) * HOUT + y) * HOUT + x0;
    o[0] = fmaxf(a0, 0.f); o[1] = fmaxf(a1, 0.f);
    o[2] = fmaxf(a2, 0.f); o[3] = fmaxf(a3, 0.f);
}

// ---------------- fc GEMM: C[64][N] += A[64][K] * W[N][K]^T, LDS-tiled, split-K ------
__global__ __launch_bounds__(256) void k_fc2(const float* __restrict__ A,
                                             const float* __restrict__ W,
                                             float* __restrict__ C,
                                             int N, int K, int kchunk)
{
    __shared__ float As[64][68];
    __shared__ float Bs[64][132];
    const int n0 = blockIdx.x * 128;
    const int kbeg = blockIdx.y * kchunk;
    const int tid = threadIdx.x;
    const int tm = tid >> 4, tn = tid & 15;
    const int am = tid >> 2, ac = tid & 3;
    const int bn = tid >> 1, bh = tid & 1;
    float acc[4][8] = {};
    for (int k0 = kbeg; k0 < kbeg + kchunk; k0 += 64) {
        #pragma unroll
        for (int q = 0; q < 4; ++q) {
            const int kk = ac * 16 + q * 4;
            const float4 v = *(const float4*)&A[(long)am * K + k0 + kk];
            As[kk + 0][am] = v.x; As[kk + 1][am] = v.y;
            As[kk + 2][am] = v.z; As[kk + 3][am] = v.w;
        }
        const int nn = n0 + bn;
        if (nn < N) {
            #pragma unroll
            for (int q = 0; q < 8; ++q) {
                const int kk = bh * 32 + q * 4;
                const float4 v = *(const float4*)&W[(long)nn * K + k0 + kk];
                Bs[kk + 0][bn] = v.x; Bs[kk + 1][bn] = v.y;
                Bs[kk + 2][bn] = v.z; Bs[kk + 3][bn] = v.w;
            }
        }
        __syncthreads();
        #pragma unroll 4
        for (int kk = 0; kk < 64; ++kk) {
            float a[4], b[8];
            #pragma unroll
            for (int i = 0; i < 4; ++i) a[i] = As[kk][tm * 4 + i];
            #pragma unroll
            for (int j = 0; j < 8; ++j) b[j] = Bs[kk][tn * 8 + j];
            #pragma unroll
            for (int i = 0; i < 4; ++i)
                #pragma unroll
                for (int j = 0; j < 8; ++j)
                    acc[i][j] = fmaf(a[i], b[j], acc[i][j]);
        }
        __syncthreads();
    }
    #pragma unroll
    for (int i = 0; i < 4; ++i) {
        const int m = tm * 4 + i;
        #pragma unroll
        for (int j = 0; j < 8; ++j) {
            const int nn = n0 + tn * 8 + j;
            if (nn < N) atomicAdd(&C[(long)m * N + nn], acc[i][j]);
        }
    }
}

__global__ __launch_bounds__(256) void k_bias_act(const float* __restrict__ C,
                                                  const float* __restrict__ bias,
                                                  float* __restrict__ out,
                                                  int N, int total, int relu)
{
    const int i = blockIdx.x * 256 + threadIdx.x;
    if (i >= total) return;
    float v = C[i] + bias[i % N];
    if (relu) v = fmaxf(v, 0.f);
    out[i] = v;
}

extern "C" void kernel_launch(void* const* d_in, const int* in_sizes, int n_in,
                              void* d_out, int out_size, void* d_ws, size_t ws_size,
                              hipStream_t stream)
{
    (void)in_sizes; (void)n_in; (void)out_size; (void)ws_size;
    const float* x       = (const float*)d_in[0];
    const float* conv1_w = (const float*)d_in[1];
    const float* conv1_b = (const float*)d_in[2];
    const float* rg_g    = (const float*)d_in[3];
    const float* rg_b    = (const float*)d_in[4];
    const float* rg_m    = (const float*)d_in[5];
    const float* rg_v    = (const float*)d_in[6];
    const float* rg_w    = (const float*)d_in[7];
    const float* rg_cb   = (const float*)d_in[8];
    const float* bn2_g   = (const float*)d_in[9];
    const float* bn2_b   = (const float*)d_in[10];
    const float* bn2_m   = (const float*)d_in[11];
    const float* bn2_v   = (const float*)d_in[12];
    const float* conv2_w = (const float*)d_in[13];
    const float* conv2_b = (const float*)d_in[14];
    const float* conv3_w = (const float*)d_in[15];
    const float* conv3_b = (const float*)d_in[16];
    const float* conv4_w = (const float*)d_in[17];
    const float* conv4_b = (const float*)d_in[18];
    const float* conv5_w = (const float*)d_in[19];
    const float* conv5_b = (const float*)d_in[20];
    const float* fc1_w   = (const float*)d_in[21];
    const float* fc1_b   = (const float*)d_in[22];
    const float* fc2_w   = (const float*)d_in[23];
    const float* fc2_b   = (const float*)d_in[24];
    const float* fc3_w   = (const float*)d_in[25];
    const float* fc3_b   = (const float*)d_in[26];

    float* ws = (float*)d_ws;
    float* h1 = ws;                     // conv1 out (64,32,132,132)
    float* hr = ws + 35684352;          // region out, same shape
    float* hp = ws;                     // pooled (64,32,66,66): reuse h1
    float* h3 = ws + 8921088;           // conv2 out
    float* h4 = h3 + 3564544;           // conv3 out
    float* h5 = h4 + 2768896;           // conv4 out
    float* h6 = h5 + 589824;            // conv5 out == fc1 input (64,6400)
    float* f1 = h6 + 409600;            // fc1 out (64,4096)
    float* f2 = f1 + 262144;            // fc2 out (64,2048)
    float* f3 = f2 + 131072;            // fc3 tmp (64,12)
    float* wt1 = hr;                    // transposed weights in dead hr region
    float* wt2 = hr + 16384;
    float* wt3 = hr + 49152;
    float* wt5 = hr + 65536;

    k_wt<<<dim3(46), 256, 0, stream>>>(conv1_w, wt1, 3, 32, 11);
    k_conv1_lds<<<dim3(33, 64), 576, 0, stream>>>(x, wt1, conv1_b, h1);
    k_region_mfma<<<dim3(64, 8), 256, 0, stream>>>(h1, rg_g, rg_b, rg_m, rg_v, rg_w, rg_cb, hr);
    k_pool_bn<<<dim3((64 * 32 * 66 * 66 + 255) / 256), 256, 0, stream>>>(hr, bn2_g, bn2_b, bn2_m, bn2_v, hp);

    k_wt<<<dim3(128), 256, 0, stream>>>(conv2_w, wt2, 32, 16, 8);
    k_wt<<<dim3(64), 256, 0, stream>>>(conv3_w, wt3, 16, 16, 8);
    k_wt<<<dim3(25), 256, 0, stream>>>(conv5_w, wt5, 16, 16, 5);

    k_convS<32, 16, 8, 66, 59, 4><<<dim3(15, 64), 256, 0, stream>>>(hp, wt2, conv2_b, h3);
    k_convS<16, 16, 8, 59, 52, 4><<<dim3(13, 64), 256, 0, stream>>>(h3, wt3, conv3_b, h4);
    k_conv<16, 6, 2, 52, 24><<<dim3(1, 16, 64), 256, 0, stream>>>(h4, conv4_w, conv4_b, h5);
    k_convS<16, 16, 5, 24, 20, 10><<<dim3(2, 64), 256, 0, stream>>>(h5, wt5, conv5_b, h6);

    hipMemsetAsync(f1, 0, 262144 * sizeof(float), stream);
    k_fc2<<<dim3(32, 10), 256, 0, stream>>>(h6, fc1_w, f1, 4096, 6400, 640);
    k_bias_act<<<dim3((262144 + 255) / 256), 256, 0, stream>>>(f1, fc1_b, f1, 4096, 262144, 1);

    hipMemsetAsync(f2, 0, 131072 * sizeof(float), stream);
    k_fc2<<<dim3(16, 16), 256, 0, stream>>>(f1, fc2_w, f2, 2048, 4096, 256);
    k_bias_act<<<dim3((131072 + 255) / 256), 256, 0, stream>>>(f2, fc2_b, f2, 2048, 131072, 1);

    hipMemsetAsync(f3, 0, 768 * sizeof(float), stream);
    k_fc2<<<dim3(1, 16), 256, 0, stream>>>(f2, fc3_w, f3, 12, 2048, 128);
    k_bias_act<<<dim3(3), 256, 0, stream>>>(f3, fc3_b, (float*)d_out, 12, 768, 0);
}

// Round 5
// 1208.904 us; speedup vs baseline: 3.4229x; 1.2106x over previous
//
#include <hip/hip_runtime.h>

#define EPS 1e-5f

typedef __attribute__((ext_vector_type(4)))  __bf16 bf16x4;
typedef __attribute__((ext_vector_type(8)))  __bf16 bf16x8;
typedef __attribute__((ext_vector_type(16))) float  f32x16;

// ---------------- weight transpose: w[co][ci][ky][kx] -> wt[ci][ky][kx][co] ----------
__global__ void k_wt(const float* __restrict__ w, float* __restrict__ wt,
                     int CIN, int COUT, int KS)
{
    const int total = COUT * CIN * KS * KS;
    const int i = blockIdx.x * 256 + threadIdx.x;
    if (i >= total) return;
    const int per = CIN * KS * KS;
    const int co = i / per, rem = i - co * per;
    wt[rem * COUT + co] = w[i];
}

// ---------------- conv1 via MFMA: (64,3,142,142) -> (64,32,132,132), k=11 ------------
// GEMM: out[co][pix] = sum_k W[co][k] act[k][pix], K re-indexed j=ky*4+ci (48, 3 chunks).
// LDS act layout s[x'][y'(33)][ci(4)] (stride 264B -> conflict-free); A in 132 VGPRs.
__global__ __launch_bounds__(256) void k_conv1_mfma(const float* __restrict__ x,
                                                    const float* __restrict__ w,
                                                    const float* __restrict__ bias,
                                                    float* __restrict__ out)
{
    __shared__ __align__(16) __bf16 sbuf[142 * 132];   // 37.5 KB; weights staged here first
    const int tid  = threadIdx.x;
    const int lane = tid & 63;
    const int wv   = tid >> 6;
    const int half = lane >> 5;
    const int l31  = lane & 31;
    const int strip = blockIdx.x;          // 6 strips of 22 output rows
    const int n     = blockIdx.y;
    const int y0    = strip * 22;

    // phase 1: stage re-laid-out weights wl[co][kx][j=ky*4+ci] (zeros at ci=3 / ky=11)
    for (int i = tid; i < 32 * 11 * 48; i += 256) {
        const int co = i / (11 * 48), r = i - co * (11 * 48);
        const int kx = r / 48, j = r - kx * 48;
        const int ky = j >> 2, ci = j & 3;
        const float v = (ci < 3 && ky < 11) ? w[((co * 3 + ci) * 11 + ky) * 11 + kx] : 0.f;
        sbuf[i] = (__bf16)v;
    }
    __syncthreads();

    // phase 2: preload A fragments (33 = 11 kx * 3 chunks) into VGPRs
    bf16x8 af[33];
    #pragma unroll
    for (int kx = 0; kx < 11; ++kx)
        #pragma unroll
        for (int c = 0; c < 3; ++c)
            af[kx * 3 + c] = *(const bf16x8*)&sbuf[(l31 * 11 + kx) * 48 + c * 16 + half * 8];
    float bias_v[16];
    #pragma unroll
    for (int r = 0; r < 16; ++r)
        bias_v[r] = bias[(r & 3) + 8 * (r >> 2) + 4 * half];
    __syncthreads();

    // phase 3: stage bf16 input strip s[x'][y'][ci], rows beyond image zeroed
    const float* xn = x + (long)n * 3 * 142 * 142;
    for (int i = tid; i < 18744; i += 256) {          // 132 q * 142 x'
        const int q = i / 142, xp = i - q * 142;
        const int yp = q >> 2, ci = q & 3;
        const int row = y0 + yp;
        const float v = (ci < 3 && row < 142) ? xn[((long)ci * 142 + row) * 142 + xp] : 0.f;
        sbuf[xp * 132 + yp * 4 + ci] = (__bf16)v;
    }
    __syncthreads();

    // phase 4: 110 tiles (22 y-rows x 5 x-tiles of 32 px), round-robin over 4 waves
    for (int u = wv; u < 110; u += 4) {
        const int yl = u / 5, xt = u - yl * 5;
        const int x0 = (xt < 4) ? xt * 32 : 100;       // last tile overlaps (recompute)
        const int px = x0 + l31;
        f32x16 acc = {};
        #pragma unroll
        for (int kx = 0; kx < 11; ++kx) {
            const int xb = (px + kx) * 132;
            #pragma unroll
            for (int c = 0; c < 3; ++c) {
                const int off = xb + (yl + c * 4 + half * 2) * 4;
                const bf16x4 lo = *(const bf16x4*)&sbuf[off];
                const bf16x4 hi = *(const bf16x4*)&sbuf[off + 4];
                const bf16x8 bf = __builtin_shufflevector(lo, hi, 0, 1, 2, 3, 4, 5, 6, 7);
                acc = __builtin_amdgcn_mfma_f32_32x32x16_bf16(af[kx * 3 + c], bf, acc, 0, 0, 0);
            }
        }
        #pragma unroll
        for (int r = 0; r < 16; ++r) {
            const int co = (r & 3) + 8 * (r >> 2) + 4 * half;
            out[(((long)n * 32 + co) * 132 + y0 + yl) * 132 + px] = acc[r] + bias_v[r];
        }
    }
}

// ---------------- generic stride-1 conv + relu, LDS-staged per-ci, transposed w ------
template <int CIN, int COUT, int KS, int HIN, int HOUT, int R>
__global__ __launch_bounds__(256) void k_convS(const float* __restrict__ in,
                                               const float* __restrict__ wt,
                                               const float* __restrict__ bias,
                                               float* __restrict__ out)
{
    constexpr int NR = R + KS - 1;
    constexpr int NPX = R * HOUT;
    __shared__ float buf[2][NR * HIN];
    const int n = blockIdx.y;
    int y0 = blockIdx.x * R; if (y0 > HOUT - R) y0 = HOUT - R;
    const int tid = threadIdx.x;
    const float* base = in + (long)n * CIN * HIN * HIN;
    for (int i = tid; i < NR * HIN; i += 256) {
        const int r = i / HIN, c = i - r * HIN;
        buf[0][i] = base[(long)(y0 + r) * HIN + c];
    }
    __syncthreads();
    const int yl = tid / HOUT, x = tid - yl * HOUT;
    float acc[COUT];
    #pragma unroll
    for (int co = 0; co < COUT; ++co) acc[co] = bias[co];
    #pragma unroll 1
    for (int ci = 0; ci < CIN; ++ci) {
        const float* cur = buf[ci & 1];
        if (ci + 1 < CIN) {
            const float* src = base + (long)(ci + 1) * HIN * HIN;
            float* nxt = buf[(ci + 1) & 1];
            for (int i = tid; i < NR * HIN; i += 256) {
                const int r = i / HIN, c = i - r * HIN;
                nxt[i] = src[(long)(y0 + r) * HIN + c];
            }
        }
        if (tid < NPX) {
            const float* wci = wt + ci * (KS * KS * COUT);
            #pragma unroll 1
            for (int ky = 0; ky < KS; ++ky) {
                const float* trow = cur + (yl + ky) * HIN + x;
                const float* wrow = wci + ky * (KS * COUT);
                #pragma unroll
                for (int kx = 0; kx < KS; ++kx) {
                    const float v = trow[kx];
                    #pragma unroll
                    for (int co = 0; co < COUT; ++co)
                        acc[co] = fmaf(wrow[kx * COUT + co], v, acc[co]);
                }
            }
        }
        __syncthreads();
    }
    if (tid < NPX) {
        #pragma unroll
        for (int co = 0; co < COUT; ++co)
            out[(((long)n * COUT + co) * HOUT + y0 + yl) * HOUT + x] = fmaxf(acc[co], 0.f);
    }
}

// ---------------- region layer via MFMA (unchanged from round 4) ---------------------
template <int TH, int TW, int NIMG>
__device__ void region_mfma_body(const float* __restrict__ h1,
                                 const float* __restrict__ gg, const float* __restrict__ bb,
                                 const float* __restrict__ mm, const float* __restrict__ vv,
                                 const float* __restrict__ ww, const float* __restrict__ cb,
                                 float* __restrict__ out,
                                 __bf16* act, __bf16* wlds,
                                 float* sc_s, float* sh_s, float* cb_s,
                                 int reg, int n0, int Y0, int X0)
{
    constexpr int PW   = TW + 2;
    constexpr int ROWS = TH + 2;
    constexpr int NP   = TH * TW;
    constexpr int NPT  = (NP + 31) / 32;
    const int tid  = threadIdx.x;
    const int lane = tid & 63;
    const int wv   = tid >> 6;
    const int half = lane >> 5;
    const int l31  = lane & 31;

    if (tid < 32) {
        const float sc = gg[reg * 32 + tid] * rsqrtf(vv[reg * 32 + tid] + EPS);
        sc_s[tid] = sc;
        sh_s[tid] = bb[reg * 32 + tid] - mm[reg * 32 + tid] * sc;
        cb_s[tid] = cb[reg * 32 + tid];
    }
    for (int i = tid; i < 9216; i += 256) {
        const int co = i / 288, r = i - co * 288;
        const int ci = r / 9, tap = r - ci * 9;
        wlds[(co * 9 + tap) * 32 + ci] = (__bf16)ww[(long)reg * 9216 + i];
    }
    for (int i = tid; i < ROWS * PW * 40; i += 256) act[i] = (__bf16)0.f;
    __syncthreads();

    bf16x8 afrag[18];
    #pragma unroll
    for (int c = 0; c < 18; ++c) {
        const int tap = c >> 1;
        const int cib = (c & 1) * 16 + half * 8;
        afrag[c] = *(const bf16x8*)&wlds[(l31 * 9 + tap) * 32 + cib];
    }

    for (int img = 0; img < NIMG; ++img) {
        const int n = n0 + img;
        for (int i = tid; i < 32 * NP; i += 256) {
            const int ci = i / NP, p = i - ci * NP;
            const int y = p / TW, x = p - y * TW;
            const float val = h1[(((long)n * 32 + ci) * 132 + Y0 + y) * 132 + X0 + x];
            const float af = fmaxf(val * sc_s[ci] + sh_s[ci], 0.f);
            act[((y + 1) * PW + (x + 1)) * 40 + ci] = (__bf16)af;
        }
        __syncthreads();
        for (int pt = wv; pt < NPT; pt += 4) {
            const int p = pt * 32 + l31;
            const bool valid = p < NP;
            const int pc = valid ? p : 0;
            const int y = pc / TW, x = pc - y * TW;
            f32x16 acc = {};
            #pragma unroll
            for (int c = 0; c < 18; ++c) {
                const int tap = c >> 1;
                const int ky = tap / 3, kx = tap - ky * 3;
                const bf16x8 bfr = *(const bf16x8*)
                    &act[((y + ky) * PW + (x + kx)) * 40 + (c & 1) * 16 + half * 8];
                acc = __builtin_amdgcn_mfma_f32_32x32x16_bf16(afrag[c], bfr, acc, 0, 0, 0);
            }
            if (valid) {
                #pragma unroll
                for (int r = 0; r < 16; ++r) {
                    const int co = (r & 3) + 8 * (r >> 2) + 4 * half;
                    const long o = (((long)n * 32 + co) * 132 + Y0 + y) * 132 + X0 + x;
                    out[o] = acc[r] + cb_s[co] + h1[o];
                }
            }
        }
        __syncthreads();
    }
}

__global__ __launch_bounds__(256) void k_region_mfma(const float* __restrict__ h1,
                                                     const float* __restrict__ gg,
                                                     const float* __restrict__ bb,
                                                     const float* __restrict__ mm,
                                                     const float* __restrict__ vv,
                                                     const float* __restrict__ ww,
                                                     const float* __restrict__ cb,
                                                     float* __restrict__ out)
{
    __shared__ __align__(16) __bf16 act[20 * 20 * 40];
    __shared__ __align__(16) __bf16 wlds[9216];
    __shared__ float sc_s[32], sh_s[32], cb_s[32];
    const int reg = blockIdx.x;
    const int ri = reg >> 3, rj = reg & 7;
    const int n0 = blockIdx.y * 8;
    const int Y0 = ri * 18, X0 = rj * 18;
    if (ri < 7 && rj < 7)
        region_mfma_body<18, 18, 8>(h1, gg, bb, mm, vv, ww, cb, out, act, wlds, sc_s, sh_s, cb_s, reg, n0, Y0, X0);
    else if (ri < 7)
        region_mfma_body<18, 6, 8>(h1, gg, bb, mm, vv, ww, cb, out, act, wlds, sc_s, sh_s, cb_s, reg, n0, Y0, X0);
    else if (rj < 7)
        region_mfma_body<6, 18, 8>(h1, gg, bb, mm, vv, ww, cb, out, act, wlds, sc_s, sh_s, cb_s, reg, n0, Y0, X0);
    else
        region_mfma_body<6, 6, 8>(h1, gg, bb, mm, vv, ww, cb, out, act, wlds, sc_s, sh_s, cb_s, reg, n0, Y0, X0);
}

// ---------------- relu -> maxpool2x2 -> bn2 ------------------------------------------
__global__ __launch_bounds__(256) void k_pool_bn(const float* __restrict__ in,
                                                 const float* __restrict__ g2,
                                                 const float* __restrict__ b2,
                                                 const float* __restrict__ m2,
                                                 const float* __restrict__ v2,
                                                 float* __restrict__ out)
{
    const int idx = blockIdx.x * 256 + threadIdx.x;
    if (idx >= 64 * 32 * 66 * 66) return;
    const int x = idx % 66;
    const int y = (idx / 66) % 66;
    const int c = (idx / (66 * 66)) % 32;
    const int n = idx / (66 * 66 * 32);
    const float2* r0 = (const float2*)(in + (((long)n * 32 + c) * 132 + 2 * y) * 132);
    const float2* r1 = r0 + 66;
    const float2 a = r0[x], b = r1[x];
    float mx = fmaxf(fmaxf(a.x, a.y), fmaxf(b.x, b.y));
    mx = fmaxf(mx, 0.f);
    out[idx] = (mx - m2[c]) * (g2[c] * rsqrtf(v2[c] + EPS)) + b2[c];
}

// ---------------- strided conv (conv4 only) ------------------------------------------
template <int CIN, int KS, int STRIDE, int HIN, int HOUT>
__global__ __launch_bounds__(256) void k_conv(const float* __restrict__ in,
                                              const float* __restrict__ w,
                                              const float* __restrict__ bias,
                                              float* __restrict__ out)
{
    const int co = blockIdx.y, n = blockIdx.z;
    constexpr int GR  = (HOUT + 3) / 4;
    constexpr int WSZ = CIN * KS * KS;
    constexpr int LEN = KS + 3 * STRIDE;
    __shared__ float ws[WSZ];
    for (int i = threadIdx.x; i < WSZ; i += 256) ws[i] = w[co * WSZ + i];
    __syncthreads();
    const int g = blockIdx.x * 256 + threadIdx.x;
    if (g >= HOUT * GR) return;
    const int y = g / GR;
    int x0 = (g - y * GR) * 4;
    if (x0 > HOUT - 4) x0 = HOUT - 4;
    float a0 = bias[co], a1 = a0, a2 = a0, a3 = a0;
    const float* base = in + (long)n * CIN * HIN * HIN;
    for (int ci = 0; ci < CIN; ++ci) {
        for (int ky = 0; ky < KS; ++ky) {
            const float* row = base + ((long)ci * HIN + y * STRIDE + ky) * HIN + x0 * STRIDE;
            float r[LEN];
            #pragma unroll
            for (int i = 0; i < LEN; ++i) r[i] = row[i];
            const float* wr = ws + (ci * KS + ky) * KS;
            #pragma unroll
            for (int kx = 0; kx < KS; ++kx) {
                const float wv = wr[kx];
                a0 = fmaf(wv, r[kx],              a0);
                a1 = fmaf(wv, r[kx + STRIDE],     a1);
                a2 = fmaf(wv, r[kx + 2 * STRIDE], a2);
                a3 = fmaf(wv, r[kx + 3 * STRIDE], a3);
            }
        }
    }
    float* o = out + (((long)n * 16 + co) * HOUT + y) * HOUT + x0;
    o[0] = fmaxf(a0, 0.f); o[1] = fmaxf(a1, 0.f);
    o[2] = fmaxf(a2, 0.f); o[3] = fmaxf(a3, 0.f);
}

// ---------------- fc GEMM: C[64][N] += A[64][K] * W[N][K]^T, LDS-tiled, split-K ------
__global__ __launch_bounds__(256) void k_fc2(const float* __restrict__ A,
                                             const float* __restrict__ W,
                                             float* __restrict__ C,
                                             int N, int K, int kchunk)
{
    __shared__ float As[64][68];
    __shared__ float Bs[64][132];
    const int n0 = blockIdx.x * 128;
    const int kbeg = blockIdx.y * kchunk;
    const int tid = threadIdx.x;
    const int tm = tid >> 4, tn = tid & 15;
    const int am = tid >> 2, ac = tid & 3;
    const int bn = tid >> 1, bh = tid & 1;
    float acc[4][8] = {};
    for (int k0 = kbeg; k0 < kbeg + kchunk; k0 += 64) {
        #pragma unroll
        for (int q = 0; q < 4; ++q) {
            const int kk = ac * 16 + q * 4;
            const float4 v = *(const float4*)&A[(long)am * K + k0 + kk];
            As[kk + 0][am] = v.x; As[kk + 1][am] = v.y;
            As[kk + 2][am] = v.z; As[kk + 3][am] = v.w;
        }
        const int nn = n0 + bn;
        if (nn < N) {
            #pragma unroll
            for (int q = 0; q < 8; ++q) {
                const int kk = bh * 32 + q * 4;
                const float4 v = *(const float4*)&W[(long)nn * K + k0 + kk];
                Bs[kk + 0][bn] = v.x; Bs[kk + 1][bn] = v.y;
                Bs[kk + 2][bn] = v.z; Bs[kk + 3][bn] = v.w;
            }
        }
        __syncthreads();
        #pragma unroll 4
        for (int kk = 0; kk < 64; ++kk) {
            float a[4], b[8];
            #pragma unroll
            for (int i = 0; i < 4; ++i) a[i] = As[kk][tm * 4 + i];
            #pragma unroll
            for (int j = 0; j < 8; ++j) b[j] = Bs[kk][tn * 8 + j];
            #pragma unroll
            for (int i = 0; i < 4; ++i)
                #pragma unroll
                for (int j = 0; j < 8; ++j)
                    acc[i][j] = fmaf(a[i], b[j], acc[i][j]);
        }
        __syncthreads();
    }
    #pragma unroll
    for (int i = 0; i < 4; ++i) {
        const int m = tm * 4 + i;
        #pragma unroll
        for (int j = 0; j < 8; ++j) {
            const int nn = n0 + tn * 8 + j;
            if (nn < N) atomicAdd(&C[(long)m * N + nn], acc[i][j]);
        }
    }
}

__global__ __launch_bounds__(256) void k_bias_act(const float* __restrict__ C,
                                                  const float* __restrict__ bias,
                                                  float* __restrict__ out,
                                                  int N, int total, int relu)
{
    const int i = blockIdx.x * 256 + threadIdx.x;
    if (i >= total) return;
    float v = C[i] + bias[i % N];
    if (relu) v = fmaxf(v, 0.f);
    out[i] = v;
}

extern "C" void kernel_launch(void* const* d_in, const int* in_sizes, int n_in,
                              void* d_out, int out_size, void* d_ws, size_t ws_size,
                              hipStream_t stream)
{
    (void)in_sizes; (void)n_in; (void)out_size; (void)ws_size;
    const float* x       = (const float*)d_in[0];
    const float* conv1_w = (const float*)d_in[1];
    const float* conv1_b = (const float*)d_in[2];
    const float* rg_g    = (const float*)d_in[3];
    const float* rg_b    = (const float*)d_in[4];
    const float* rg_m    = (const float*)d_in[5];
    const float* rg_v    = (const float*)d_in[6];
    const float* rg_w    = (const float*)d_in[7];
    const float* rg_cb   = (const float*)d_in[8];
    const float* bn2_g   = (const float*)d_in[9];
    const float* bn2_b   = (const float*)d_in[10];
    const float* bn2_m   = (const float*)d_in[11];
    const float* bn2_v   = (const float*)d_in[12];
    const float* conv2_w = (const float*)d_in[13];
    const float* conv2_b = (const float*)d_in[14];
    const float* conv3_w = (const float*)d_in[15];
    const float* conv3_b = (const float*)d_in[16];
    const float* conv4_w = (const float*)d_in[17];
    const float* conv4_b = (const float*)d_in[18];
    const float* conv5_w = (const float*)d_in[19];
    const float* conv5_b = (const float*)d_in[20];
    const float* fc1_w   = (const float*)d_in[21];
    const float* fc1_b   = (const float*)d_in[22];
    const float* fc2_w   = (const float*)d_in[23];
    const float* fc2_b   = (const float*)d_in[24];
    const float* fc3_w   = (const float*)d_in[25];
    const float* fc3_b   = (const float*)d_in[26];

    float* ws = (float*)d_ws;
    float* h1 = ws;                     // conv1 out (64,32,132,132)
    float* hr = ws + 35684352;          // region out, same shape
    float* hp = ws;                     // pooled (64,32,66,66): reuse h1
    float* h3 = ws + 8921088;           // conv2 out
    float* h4 = h3 + 3564544;           // conv3 out
    float* h5 = h4 + 2768896;           // conv4 out
    float* h6 = h5 + 589824;            // conv5 out == fc1 input (64,6400)
    float* f1 = h6 + 409600;            // fc1 out (64,4096)
    float* f2 = f1 + 262144;            // fc2 out (64,2048)
    float* f3 = f2 + 131072;            // fc3 tmp (64,12)
    float* wt2 = hr + 16384;            // transposed weights in dead hr region
    float* wt3 = hr + 49152;
    float* wt5 = hr + 65536;

    k_conv1_mfma<<<dim3(6, 64), 256, 0, stream>>>(x, conv1_w, conv1_b, h1);
    k_region_mfma<<<dim3(64, 8), 256, 0, stream>>>(h1, rg_g, rg_b, rg_m, rg_v, rg_w, rg_cb, hr);
    k_pool_bn<<<dim3((64 * 32 * 66 * 66 + 255) / 256), 256, 0, stream>>>(hr, bn2_g, bn2_b, bn2_m, bn2_v, hp);

    k_wt<<<dim3(128), 256, 0, stream>>>(conv2_w, wt2, 32, 16, 8);
    k_wt<<<dim3(64), 256, 0, stream>>>(conv3_w, wt3, 16, 16, 8);
    k_wt<<<dim3(25), 256, 0, stream>>>(conv5_w, wt5, 16, 16, 5);

    k_convS<32, 16, 8, 66, 59, 4><<<dim3(15, 64), 256, 0, stream>>>(hp, wt2, conv2_b, h3);
    k_convS<16, 16, 8, 59, 52, 4><<<dim3(13, 64), 256, 0, stream>>>(h3, wt3, conv3_b, h4);
    k_conv<16, 6, 2, 52, 24><<<dim3(1, 16, 64), 256, 0, stream>>>(h4, conv4_w, conv4_b, h5);
    k_convS<16, 16, 5, 24, 20, 10><<<dim3(2, 64), 256, 0, stream>>>(h5, wt5, conv5_b, h6);

    hipMemsetAsync(f1, 0, 262144 * sizeof(float), stream);
    k_fc2<<<dim3(32, 10), 256, 0, stream>>>(h6, fc1_w, f1, 4096, 6400, 640);
    k_bias_act<<<dim3((262144 + 255) / 256), 256, 0, stream>>>(f1, fc1_b, f1, 4096, 262144, 1);

    hipMemsetAsync(f2, 0, 131072 * sizeof(float), stream);
    k_fc2<<<dim3(16, 16), 256, 0, stream>>>(f1, fc2_w, f2, 2048, 4096, 256);
    k_bias_act<<<dim3((131072 + 255) / 256), 256, 0, stream>>>(f2, fc2_b, f2, 2048, 131072, 1);

    hipMemsetAsync(f3, 0, 768 * sizeof(float), stream);
    k_fc2<<<dim3(1, 16), 256, 0, stream>>>(f2, fc3_w, f3, 12, 2048, 128);
    k_bias_act<<<dim3(3), 256, 0, stream>>>(f3, fc3_b, (float*)d_out, 12, 768, 0);
}

// Round 6
// 1012.826 us; speedup vs baseline: 4.0855x; 1.1936x over previous
//
#include <hip/hip_runtime.h>

#define EPS 1e-5f

typedef __attribute__((ext_vector_type(4)))  __bf16 bf16x4;
typedef __attribute__((ext_vector_type(8)))  __bf16 bf16x8;
typedef __attribute__((ext_vector_type(4)))  float  f32x4;
typedef __attribute__((ext_vector_type(16))) float  f32x16;

// ---------------- conv1 via MFMA: (64,3,142,142) -> (64,32,132,132), k=11 ------------
__global__ __launch_bounds__(256) void k_conv1_mfma(const float* __restrict__ x,
                                                    const float* __restrict__ w,
                                                    const float* __restrict__ bias,
                                                    float* __restrict__ out)
{
    __shared__ __align__(16) __bf16 sbuf[142 * 132];
    const int tid  = threadIdx.x;
    const int lane = tid & 63;
    const int wv   = tid >> 6;
    const int half = lane >> 5;
    const int l31  = lane & 31;
    const int strip = blockIdx.x;
    const int n     = blockIdx.y;
    const int y0    = strip * 22;

    for (int i = tid; i < 32 * 11 * 48; i += 256) {
        const int co = i / (11 * 48), r = i - co * (11 * 48);
        const int kx = r / 48, j = r - kx * 48;
        const int ky = j >> 2, ci = j & 3;
        const float v = (ci < 3 && ky < 11) ? w[((co * 3 + ci) * 11 + ky) * 11 + kx] : 0.f;
        sbuf[i] = (__bf16)v;
    }
    __syncthreads();

    bf16x8 af[33];
    #pragma unroll
    for (int kx = 0; kx < 11; ++kx)
        #pragma unroll
        for (int c = 0; c < 3; ++c)
            af[kx * 3 + c] = *(const bf16x8*)&sbuf[(l31 * 11 + kx) * 48 + c * 16 + half * 8];
    float bias_v[16];
    #pragma unroll
    for (int r = 0; r < 16; ++r)
        bias_v[r] = bias[(r & 3) + 8 * (r >> 2) + 4 * half];
    __syncthreads();

    const float* xn = x + (long)n * 3 * 142 * 142;
    for (int i = tid; i < 18744; i += 256) {
        const int q = i / 142, xp = i - q * 142;
        const int yp = q >> 2, ci = q & 3;
        const int row = y0 + yp;
        const float v = (ci < 3 && row < 142) ? xn[((long)ci * 142 + row) * 142 + xp] : 0.f;
        sbuf[xp * 132 + yp * 4 + ci] = (__bf16)v;
    }
    __syncthreads();

    for (int u = wv; u < 110; u += 4) {
        const int yl = u / 5, xt = u - yl * 5;
        const int x0 = (xt < 4) ? xt * 32 : 100;
        const int px = x0 + l31;
        f32x16 acc = {};
        #pragma unroll
        for (int kx = 0; kx < 11; ++kx) {
            const int xb = (px + kx) * 132;
            #pragma unroll
            for (int c = 0; c < 3; ++c) {
                const int off = xb + (yl + c * 4 + half * 2) * 4;
                const bf16x4 lo = *(const bf16x4*)&sbuf[off];
                const bf16x4 hi = *(const bf16x4*)&sbuf[off + 4];
                const bf16x8 bf = __builtin_shufflevector(lo, hi, 0, 1, 2, 3, 4, 5, 6, 7);
                acc = __builtin_amdgcn_mfma_f32_32x32x16_bf16(af[kx * 3 + c], bf, acc, 0, 0, 0);
            }
        }
        #pragma unroll
        for (int r = 0; r < 16; ++r) {
            const int co = (r & 3) + 8 * (r >> 2) + 4 * half;
            out[(((long)n * 32 + co) * 132 + y0 + yl) * 132 + px] = acc[r] + bias_v[r];
        }
    }
}

// ---------------- region layer via MFMA, stride-36 LDS (conflict-free) ---------------
template <int TH, int TW, int NIMG>
__device__ void region_mfma_body(const float* __restrict__ h1,
                                 const float* __restrict__ gg, const float* __restrict__ bb,
                                 const float* __restrict__ mm, const float* __restrict__ vv,
                                 const float* __restrict__ ww, const float* __restrict__ cb,
                                 float* __restrict__ out,
                                 __bf16* act, __bf16* wlds,
                                 float* sc_s, float* sh_s, float* cb_s,
                                 int reg, int n0, int Y0, int X0)
{
    constexpr int PW   = TW + 2;
    constexpr int ROWS = TH + 2;
    constexpr int NP   = TH * TW;
    constexpr int NPT  = (NP + 31) / 32;
    const int tid  = threadIdx.x;
    const int lane = tid & 63;
    const int wv   = tid >> 6;
    const int half = lane >> 5;
    const int l31  = lane & 31;

    if (tid < 32) {
        const float sc = gg[reg * 32 + tid] * rsqrtf(vv[reg * 32 + tid] + EPS);
        sc_s[tid] = sc;
        sh_s[tid] = bb[reg * 32 + tid] - mm[reg * 32 + tid] * sc;
        cb_s[tid] = cb[reg * 32 + tid];
    }
    for (int i = tid; i < 9216; i += 256) {
        const int co = i / 288, r = i - co * 288;
        const int ci = r / 9, tap = r - ci * 9;
        wlds[(co * 9 + tap) * 32 + ci] = (__bf16)ww[(long)reg * 9216 + i];
    }
    for (int i = tid; i < ROWS * PW * 36; i += 256) act[i] = (__bf16)0.f;
    __syncthreads();

    bf16x8 afrag[18];
    #pragma unroll
    for (int c = 0; c < 18; ++c) {
        const int tap = c >> 1;
        const int cib = (c & 1) * 16 + half * 8;
        afrag[c] = *(const bf16x8*)&wlds[(l31 * 9 + tap) * 32 + cib];
    }

    for (int img = 0; img < NIMG; ++img) {
        const int n = n0 + img;
        for (int i = tid; i < 32 * NP; i += 256) {
            const int ci = i / NP, p = i - ci * NP;
            const int y = p / TW, x = p - y * TW;
            const float val = h1[(((long)n * 32 + ci) * 132 + Y0 + y) * 132 + X0 + x];
            const float af = fmaxf(val * sc_s[ci] + sh_s[ci], 0.f);
            act[((y + 1) * PW + (x + 1)) * 36 + ci] = (__bf16)af;
        }
        __syncthreads();
        for (int pt = wv; pt < NPT; pt += 4) {
            const int p = pt * 32 + l31;
            const bool valid = p < NP;
            const int pc = valid ? p : 0;
            const int y = pc / TW, x = pc - y * TW;
            f32x16 acc = {};
            #pragma unroll
            for (int c = 0; c < 18; ++c) {
                const int tap = c >> 1;
                const int ky = tap / 3, kx = tap - ky * 3;
                const int off = ((y + ky) * PW + (x + kx)) * 36 + (c & 1) * 16 + half * 8;
                const bf16x4 lo = *(const bf16x4*)&act[off];
                const bf16x4 hi = *(const bf16x4*)&act[off + 4];
                const bf16x8 bfr = __builtin_shufflevector(lo, hi, 0, 1, 2, 3, 4, 5, 6, 7);
                acc = __builtin_amdgcn_mfma_f32_32x32x16_bf16(afrag[c], bfr, acc, 0, 0, 0);
            }
            if (valid) {
                #pragma unroll
                for (int r = 0; r < 16; ++r) {
                    const int co = (r & 3) + 8 * (r >> 2) + 4 * half;
                    const long o = (((long)n * 32 + co) * 132 + Y0 + y) * 132 + X0 + x;
                    out[o] = acc[r] + cb_s[co] + h1[o];
                }
            }
        }
        __syncthreads();
    }
}

__global__ __launch_bounds__(256) void k_region_mfma(const float* __restrict__ h1,
                                                     const float* __restrict__ gg,
                                                     const float* __restrict__ bb,
                                                     const float* __restrict__ mm,
                                                     const float* __restrict__ vv,
                                                     const float* __restrict__ ww,
                                                     const float* __restrict__ cb,
                                                     float* __restrict__ out)
{
    __shared__ __align__(16) __bf16 act[20 * 20 * 36];   // 28.8 KB
    __shared__ __align__(16) __bf16 wlds[9216];          // 18.4 KB
    __shared__ float sc_s[32], sh_s[32], cb_s[32];
    const int reg = blockIdx.x;
    const int ri = reg >> 3, rj = reg & 7;
    const int n0 = blockIdx.y * 8;
    const int Y0 = ri * 18, X0 = rj * 18;
    if (ri < 7 && rj < 7)
        region_mfma_body<18, 18, 8>(h1, gg, bb, mm, vv, ww, cb, out, act, wlds, sc_s, sh_s, cb_s, reg, n0, Y0, X0);
    else if (ri < 7)
        region_mfma_body<18, 6, 8>(h1, gg, bb, mm, vv, ww, cb, out, act, wlds, sc_s, sh_s, cb_s, reg, n0, Y0, X0);
    else if (rj < 7)
        region_mfma_body<6, 18, 8>(h1, gg, bb, mm, vv, ww, cb, out, act, wlds, sc_s, sh_s, cb_s, reg, n0, Y0, X0);
    else
        region_mfma_body<6, 6, 8>(h1, gg, bb, mm, vv, ww, cb, out, act, wlds, sc_s, sh_s, cb_s, reg, n0, Y0, X0);
}

// ---------------- relu -> maxpool2x2 -> bn2 ------------------------------------------
__global__ __launch_bounds__(256) void k_pool_bn(const float* __restrict__ in,
                                                 const float* __restrict__ g2,
                                                 const float* __restrict__ b2,
                                                 const float* __restrict__ m2,
                                                 const float* __restrict__ v2,
                                                 float* __restrict__ out)
{
    const int idx = blockIdx.x * 256 + threadIdx.x;
    if (idx >= 64 * 32 * 66 * 66) return;
    const int x = idx % 66;
    const int y = (idx / 66) % 66;
    const int c = (idx / (66 * 66)) % 32;
    const int n = idx / (66 * 66 * 32);
    const float2* r0 = (const float2*)(in + (((long)n * 32 + c) * 132 + 2 * y) * 132);
    const float2* r1 = r0 + 66;
    const float2 a = r0[x], b = r1[x];
    float mx = fmaxf(fmaxf(a.x, a.y), fmaxf(b.x, b.y));
    mx = fmaxf(mx, 0.f);
    out[idx] = (mx - m2[c]) * (g2[c] * rsqrtf(v2[c] + EPS)) + b2[c];
}

// ---------------- weight prep for MFMA convs: w[co][ci][ky][kx] -> frag order --------
// wA[((g*NCHUNK + ch)*4 + quad)*128 + co*8 + j], k = ch*32+quad*8+j, t=k/16, c=k%16.
__global__ void k_wprep(const float* __restrict__ w, __bf16* __restrict__ wA,
                        int CIN, int KS, int NCHUNK)
{
    const int NG = CIN / 16;
    const int total = NG * NCHUNK * 512;
    const int i = blockIdx.x * 256 + threadIdx.x;
    if (i >= total) return;
    const int j   = i & 7;
    const int co  = (i >> 3) & 15;
    const int quad = (i >> 7) & 3;
    const int ch  = (i >> 9) % NCHUNK;
    const int g   = (i >> 9) / NCHUNK;
    const int k   = ch * 32 + quad * 8 + j;
    const int t   = k >> 4, c = k & 15;
    float v = 0.f;
    if (t < KS * KS) v = w[((co * CIN + g * 16 + c) * KS + t / KS) * KS + t % KS];
    wA[i] = (__bf16)v;
}

// ---------------- stride-1 conv + relu via MFMA 16x16x32, COUT=16 --------------------
template <int CIN, int KS, int HIN, int HOUT, int R>
__global__ __launch_bounds__(256) void k_conv_mfma(const float* __restrict__ in,
                                                   const __bf16* __restrict__ wA,
                                                   const float* __restrict__ bias,
                                                   float* __restrict__ out)
{
    constexpr int NG     = CIN / 16;
    constexpr int TAPS   = KS * KS;
    constexpr int NCHUNK = (TAPS * 16 + 31) / 32;      // per ci-group
    constexpr int NROWS  = R + KS - 1;
    constexpr int NP     = R * HOUT;
    constexpr int NTIL   = (NP + 15) / 16;
    constexpr int NT     = (NTIL + 3) / 4;
    __shared__ __align__(16) __bf16 act[NROWS * HIN * 20];
    __shared__ __align__(16) __bf16 wl[NCHUNK * 512];
    const int tid  = threadIdx.x;
    const int lane = tid & 63;
    const int wv   = tid >> 6;
    const int quad = lane >> 4;
    const int m    = lane & 15;
    const int n    = blockIdx.y;
    int y0 = blockIdx.x * R; if (y0 > HOUT - R) y0 = HOUT - R;

    int yl[NT], xx[NT]; bool val[NT];
    #pragma unroll
    for (int t = 0; t < NT; ++t) {
        const int til = wv + t * 4;
        int p = til * 16 + m;
        val[t] = (til < NTIL) && (p < NP);
        if (!val[t]) p = m;
        yl[t] = p / HOUT; xx[t] = p - yl[t] * HOUT;
    }
    f32x4 acc[NT];
    #pragma unroll
    for (int t = 0; t < NT; ++t) acc[t] = (f32x4){0.f, 0.f, 0.f, 0.f};

    for (int g = 0; g < NG; ++g) {
        if (g) __syncthreads();
        for (int i = tid; i < NCHUNK * 256; i += 256)
            ((unsigned*)wl)[i] = ((const unsigned*)wA)[g * NCHUNK * 256 + i];
        for (int i = tid; i < 16 * NROWS * HIN; i += 256) {
            const int c = i / (NROWS * HIN), px = i - c * (NROWS * HIN);
            const int r = px / HIN, xc = px - r * HIN;
            const float v = in[(((long)n * CIN + g * 16 + c) * HIN + y0 + r) * HIN + xc];
            act[px * 20 + c] = (__bf16)v;
        }
        __syncthreads();
        for (int ch = 0; ch < NCHUNK; ++ch) {
            const bf16x8 a = *(const bf16x8*)&wl[(ch * 4 + quad) * 128 + m * 8];
            const int kbase = ch * 32 + quad * 8;
            int t = kbase >> 4;
            const int c0 = kbase & 15;                 // 0 or 8
            int ky = 0, kx = 0;
            if (t < TAPS) { ky = t / KS; kx = t - ky * KS; }
            #pragma unroll
            for (int tt = 0; tt < NT; ++tt) {
                const int off = ((yl[tt] + ky) * HIN + xx[tt] + kx) * 20 + c0;
                const bf16x4 lo = *(const bf16x4*)&act[off];
                const bf16x4 hi = *(const bf16x4*)&act[off + 4];
                const bf16x8 b = __builtin_shufflevector(lo, hi, 0, 1, 2, 3, 4, 5, 6, 7);
                acc[tt] = __builtin_amdgcn_mfma_f32_16x16x32_bf16(a, b, acc[tt], 0, 0, 0);
            }
        }
    }
    #pragma unroll
    for (int tt = 0; tt < NT; ++tt) {
        if (!val[tt]) continue;
        #pragma unroll
        for (int r = 0; r < 4; ++r) {
            const int co = quad * 4 + r;
            out[(((long)n * 16 + co) * HOUT + y0 + yl[tt]) * HOUT + xx[tt]]
                = fmaxf(acc[tt][r] + bias[co], 0.f);
        }
    }
}

// ---------------- strided conv (conv4 only) ------------------------------------------
template <int CIN, int KS, int STRIDE, int HIN, int HOUT>
__global__ __launch_bounds__(256) void k_conv(const float* __restrict__ in,
                                              const float* __restrict__ w,
                                              const float* __restrict__ bias,
                                              float* __restrict__ out)
{
    const int co = blockIdx.y, n = blockIdx.z;
    constexpr int GR  = (HOUT + 3) / 4;
    constexpr int WSZ = CIN * KS * KS;
    constexpr int LEN = KS + 3 * STRIDE;
    __shared__ float ws[WSZ];
    for (int i = threadIdx.x; i < WSZ; i += 256) ws[i] = w[co * WSZ + i];
    __syncthreads();
    const int g = blockIdx.x * 256 + threadIdx.x;
    if (g >= HOUT * GR) return;
    const int y = g / GR;
    int x0 = (g - y * GR) * 4;
    if (x0 > HOUT - 4) x0 = HOUT - 4;
    float a0 = bias[co], a1 = a0, a2 = a0, a3 = a0;
    const float* base = in + (long)n * CIN * HIN * HIN;
    for (int ci = 0; ci < CIN; ++ci) {
        for (int ky = 0; ky < KS; ++ky) {
            const float* row = base + ((long)ci * HIN + y * STRIDE + ky) * HIN + x0 * STRIDE;
            float r[LEN];
            #pragma unroll
            for (int i = 0; i < LEN; ++i) r[i] = row[i];
            const float* wr = ws + (ci * KS + ky) * KS;
            #pragma unroll
            for (int kx = 0; kx < KS; ++kx) {
                const float wv = wr[kx];
                a0 = fmaf(wv, r[kx],              a0);
                a1 = fmaf(wv, r[kx + STRIDE],     a1);
                a2 = fmaf(wv, r[kx + 2 * STRIDE], a2);
                a3 = fmaf(wv, r[kx + 3 * STRIDE], a3);
            }
        }
    }
    float* o = out + (((long)n * 16 + co) * HOUT + y) * HOUT + x0;
    o[0] = fmaxf(a0, 0.f); o[1] = fmaxf(a1, 0.f);
    o[2] = fmaxf(a2, 0.f); o[3] = fmaxf(a3, 0.f);
}

// ---------------- fc GEMM: C[64][N] += A[64][K] * W[N][K]^T, LDS-tiled, split-K ------
__global__ __launch_bounds__(256) void k_fc2(const float* __restrict__ A,
                                             const float* __restrict__ W,
                                             float* __restrict__ C,
                                             int N, int K, int kchunk)
{
    __shared__ float As[64][68];
    __shared__ float Bs[64][132];
    const int n0 = blockIdx.x * 128;
    const int kbeg = blockIdx.y * kchunk;
    const int tid = threadIdx.x;
    const int tm = tid >> 4, tn = tid & 15;
    const int am = tid >> 2, ac = tid & 3;
    const int bn = tid >> 1, bh = tid & 1;
    float acc[4][8] = {};
    for (int k0 = kbeg; k0 < kbeg + kchunk; k0 += 64) {
        #pragma unroll
        for (int q = 0; q < 4; ++q) {
            const int kk = ac * 16 + q * 4;
            const float4 v = *(const float4*)&A[(long)am * K + k0 + kk];
            As[kk + 0][am] = v.x; As[kk + 1][am] = v.y;
            As[kk + 2][am] = v.z; As[kk + 3][am] = v.w;
        }
        const int nn = n0 + bn;
        if (nn < N) {
            #pragma unroll
            for (int q = 0; q < 8; ++q) {
                const int kk = bh * 32 + q * 4;
                const float4 v = *(const float4*)&W[(long)nn * K + k0 + kk];
                Bs[kk + 0][bn] = v.x; Bs[kk + 1][bn] = v.y;
                Bs[kk + 2][bn] = v.z; Bs[kk + 3][bn] = v.w;
            }
        }
        __syncthreads();
        #pragma unroll 4
        for (int kk = 0; kk < 64; ++kk) {
            float a[4], b[8];
            #pragma unroll
            for (int i = 0; i < 4; ++i) a[i] = As[kk][tm * 4 + i];
            #pragma unroll
            for (int j = 0; j < 8; ++j) b[j] = Bs[kk][tn * 8 + j];
            #pragma unroll
            for (int i = 0; i < 4; ++i)
                #pragma unroll
                for (int j = 0; j < 8; ++j)
                    acc[i][j] = fmaf(a[i], b[j], acc[i][j]);
        }
        __syncthreads();
    }
    #pragma unroll
    for (int i = 0; i < 4; ++i) {
        const int m = tm * 4 + i;
        #pragma unroll
        for (int j = 0; j < 8; ++j) {
            const int nn = n0 + tn * 8 + j;
            if (nn < N) atomicAdd(&C[(long)m * N + nn], acc[i][j]);
        }
    }
}

__global__ __launch_bounds__(256) void k_bias_act(const float* __restrict__ C,
                                                  const float* __restrict__ bias,
                                                  float* __restrict__ out,
                                                  int N, int total, int relu)
{
    const int i = blockIdx.x * 256 + threadIdx.x;
    if (i >= total) return;
    float v = C[i] + bias[i % N];
    if (relu) v = fmaxf(v, 0.f);
    out[i] = v;
}

extern "C" void kernel_launch(void* const* d_in, const int* in_sizes, int n_in,
                              void* d_out, int out_size, void* d_ws, size_t ws_size,
                              hipStream_t stream)
{
    (void)in_sizes; (void)n_in; (void)out_size; (void)ws_size;
    const float* x       = (const float*)d_in[0];
    const float* conv1_w = (const float*)d_in[1];
    const float* conv1_b = (const float*)d_in[2];
    const float* rg_g    = (const float*)d_in[3];
    const float* rg_b    = (const float*)d_in[4];
    const float* rg_m    = (const float*)d_in[5];
    const float* rg_v    = (const float*)d_in[6];
    const float* rg_w    = (const float*)d_in[7];
    const float* rg_cb   = (const float*)d_in[8];
    const float* bn2_g   = (const float*)d_in[9];
    const float* bn2_b   = (const float*)d_in[10];
    const float* bn2_m   = (const float*)d_in[11];
    const float* bn2_v   = (const float*)d_in[12];
    const float* conv2_w = (const float*)d_in[13];
    const float* conv2_b = (const float*)d_in[14];
    const float* conv3_w = (const float*)d_in[15];
    const float* conv3_b = (const float*)d_in[16];
    const float* conv4_w = (const float*)d_in[17];
    const float* conv4_b = (const float*)d_in[18];
    const float* conv5_w = (const float*)d_in[19];
    const float* conv5_b = (const float*)d_in[20];
    const float* fc1_w   = (const float*)d_in[21];
    const float* fc1_b   = (const float*)d_in[22];
    const float* fc2_w   = (const float*)d_in[23];
    const float* fc2_b   = (const float*)d_in[24];
    const float* fc3_w   = (const float*)d_in[25];
    const float* fc3_b   = (const float*)d_in[26];

    float* ws = (float*)d_ws;
    float* h1 = ws;                     // conv1 out (64,32,132,132)
    float* hr = ws + 35684352;          // region out, same shape
    float* hp = ws;                     // pooled (64,32,66,66): reuse h1
    float* h3 = ws + 8921088;           // conv2 out
    float* h4 = h3 + 3564544;           // conv3 out
    float* h5 = h4 + 2768896;           // conv4 out
    float* h6 = h5 + 589824;            // conv5 out == fc1 input (64,6400)
    float* f1 = h6 + 409600;            // fc1 out (64,4096)
    float* f2 = f1 + 262144;            // fc2 out (64,2048)
    float* f3 = f2 + 131072;            // fc3 tmp (64,12)
    // permuted bf16 conv weights in dead hr region (written after pool_bn)
    __bf16* wA2 = (__bf16*)(hr + 16384);   // 2 groups * 32 ch * 512 = 32768 bf16
    __bf16* wA3 = (__bf16*)(hr + 32768);   // 16384 bf16
    __bf16* wA5 = (__bf16*)(hr + 40960);   // 6656 bf16

    k_conv1_mfma<<<dim3(6, 64), 256, 0, stream>>>(x, conv1_w, conv1_b, h1);
    k_region_mfma<<<dim3(64, 8), 256, 0, stream>>>(h1, rg_g, rg_b, rg_m, rg_v, rg_w, rg_cb, hr);
    k_pool_bn<<<dim3((64 * 32 * 66 * 66 + 255) / 256), 256, 0, stream>>>(hr, bn2_g, bn2_b, bn2_m, bn2_v, hp);

    k_wprep<<<dim3(128), 256, 0, stream>>>(conv2_w, wA2, 32, 8, 32);
    k_wprep<<<dim3(64), 256, 0, stream>>>(conv3_w, wA3, 16, 8, 32);
    k_wprep<<<dim3(26), 256, 0, stream>>>(conv5_w, wA5, 16, 5, 13);

    k_conv_mfma<32, 8, 66, 59, 4><<<dim3(15, 64), 256, 0, stream>>>(hp, wA2, conv2_b, h3);
    k_conv_mfma<16, 8, 59, 52, 4><<<dim3(13, 64), 256, 0, stream>>>(h3, wA3, conv3_b, h4);
    k_conv<16, 6, 2, 52, 24><<<dim3(1, 16, 64), 256, 0, stream>>>(h4, conv4_w, conv4_b, h5);
    k_conv_mfma<16, 5, 24, 20, 10><<<dim3(2, 64), 256, 0, stream>>>(h5, wA5, conv5_b, h6);

    hipMemsetAsync(f1, 0, 262144 * sizeof(float), stream);
    k_fc2<<<dim3(32, 10), 256, 0, stream>>>(h6, fc1_w, f1, 4096, 6400, 640);
    k_bias_act<<<dim3((262144 + 255) / 256), 256, 0, stream>>>(f1, fc1_b, f1, 4096, 262144, 1);

    hipMemsetAsync(f2, 0, 131072 * sizeof(float), stream);
    k_fc2<<<dim3(16, 16), 256, 0, stream>>>(f1, fc2_w, f2, 2048, 4096, 256);
    k_bias_act<<<dim3((131072 + 255) / 256), 256, 0, stream>>>(f2, fc2_b, f2, 2048, 131072, 1);

    hipMemsetAsync(f3, 0, 768 * sizeof(float), stream);
    k_fc2<<<dim3(1, 16), 256, 0, stream>>>(f2, fc3_w, f3, 12, 2048, 128);
    k_bias_act<<<dim3(3), 256, 0, stream>>>(f3, fc3_b, (float*)d_out, 12, 768, 0);
}